// Round 1
// baseline (1298.117 us; speedup 1.0000x reference)
//
#include <hip/hip_runtime.h>
#include <cmath>

#define BATCH 4
#define HGT 512
#define WID 512
#define PIX (HGT*WID)        // 262144 = 2^18
#define NPIX (BATCH*PIX)     // 1048576

// ---------- ws layout (bytes) ----------
constexpr size_t OFF_SAL   = 0;                          // NPIX f32
constexpr size_t OFF_T1    = OFF_SAL   + (size_t)NPIX*4;
constexpr size_t OFF_T2    = OFF_T1    + (size_t)NPIX*4;
constexpr size_t OFF_ML    = OFF_T2    + (size_t)NPIX*4; // NPIX u8
constexpr size_t OFF_HALO  = OFF_ML    + (size_t)NPIX;
constexpr size_t OFF_DECAY = OFF_HALO  + (size_t)NPIX;
constexpr size_t OFF_H1    = OFF_DECAY + (size_t)NPIX;             // BATCH*65536 u32
constexpr size_t OFF_H2    = OFF_H1    + (size_t)BATCH*65536*4;    // BATCH*6*65536 u32
constexpr size_t OFF_STATE = OFF_H2    + (size_t)BATCH*6*65536*4;  // BATCH*8 int2
constexpr size_t OFF_OSTAT = OFF_STATE + (size_t)BATCH*8*8;        // BATCH*8 f32
constexpr size_t OFF_SCAL  = OFF_OSTAT + (size_t)BATCH*8*4;        // BATCH*8 f32
constexpr size_t OFF_PL1   = OFF_SCAL  + (size_t)BATCH*8*4;        // 4096 f32
constexpr size_t OFF_PG    = OFF_PL1   + 4096*4;                   // 1024 f32
constexpr size_t OFF_PSA   = OFF_PG    + 1024*4;
constexpr size_t OFF_PSB   = OFF_PSA   + 1024*4;
constexpr size_t OFF_P4    = OFF_PSB   + 1024*4;                   // 1024*4 f32

// scalar slots per image (index b*8+slot)
#define S_THR_IR 0
#define S_THR_VIS 1
#define S_THR_SUP 2
#define S_Q97A 3
#define S_Q97B 4
#define S_Q90S 5
#define S_Q97S 6
#define S_SALSUM 7

struct RanksArg { int r[6]; int nr; };
struct GaussArg { float g[11]; };

__device__ __forceinline__ unsigned keymap(float x){
  unsigned u = __float_as_uint(x);
  return (u & 0x80000000u) ? ~u : (u | 0x80000000u);
}
__device__ __forceinline__ float invkey(unsigned k){
  unsigned bits = (k & 0x80000000u) ? (k ^ 0x80000000u) : ~k;
  return __uint_as_float(bits);
}

// ---------- saliency pools (separable, truncated SAME windows) ----------
template<int MIN>
__global__ void pool_x_k(const float* __restrict__ src, float* __restrict__ dst, int r){
  int i = blockIdx.x*256 + threadIdx.x;
  if (i >= NPIX) return;
  int x = i & (WID-1); int rb = i - x;
  int lo = x - r; if (lo < 0) lo = 0;
  int hi = x + r; if (hi > WID-1) hi = WID-1;
  float v = MIN ? 3.4e38f : -3.4e38f;
  for (int xx = lo; xx <= hi; ++xx){
    float s = src[rb + xx];
    v = MIN ? fminf(v, s) : fmaxf(v, s);
  }
  dst[i] = v;
}

template<int MIN>
__global__ void pool_y_k(const float* __restrict__ src, float* __restrict__ dst, int r){
  int i = blockIdx.x*256 + threadIdx.x;
  if (i >= NPIX) return;
  int b = i >> 18; int rem = i & (PIX-1);
  int y = rem >> 9; int x = rem & (WID-1);
  int lo = y - r; if (lo < 0) lo = 0;
  int hi = y + r; if (hi > HGT-1) hi = HGT-1;
  const float* sp = src + ((size_t)b << 18) + x;
  float v = MIN ? 3.4e38f : -3.4e38f;
  for (int yy = lo; yy <= hi; ++yy){
    float s = sp[yy << 9];
    v = MIN ? fminf(v, s) : fmaxf(v, s);
  }
  dst[i] = v;
}

__global__ void sal_update_k(float* __restrict__ sal, const float* __restrict__ A,
                             const float* __restrict__ open_, int first){
  int i = blockIdx.x*256 + threadIdx.x;
  if (i >= NPIX) return;
  float s = A[i] - open_[i];
  sal[i] = first ? s : fmaxf(sal[i], s);
}

__global__ __launch_bounds__(1024) void sal_sum_k(const float* __restrict__ sal, float* scal){
  __shared__ float red[1024];
  int b = blockIdx.x, t = threadIdx.x;
  float s = 0.f;
  const float* sp = sal + (size_t)b*PIX;
  for (int i = t; i < PIX; i += 1024) s += sp[i];
  red[t] = s; __syncthreads();
  for (int o = 512; o > 0; o >>= 1){ if (t < o) red[t] += red[t+o]; __syncthreads(); }
  if (t == 0) scal[b*8 + S_SALSUM] = red[0];
}

__global__ void sal_norm_k(float* __restrict__ sal, const float* __restrict__ scal){
  int i = blockIdx.x*256 + threadIdx.x;
  if (i >= NPIX) return;
  int b = i >> 18;
  float mean = scal[b*8 + S_SALSUM] * (1.0f/(float)PIX);
  sal[i] = sal[i] / (mean + 1e-6f);
}

// ---------- exact quantile: two-level histogram select ----------
__global__ void hist16_k(const float* __restrict__ X, unsigned* __restrict__ hist){
  int i = blockIdx.x*256 + threadIdx.x;
  if (i >= NPIX) return;
  int b = i >> 18;
  unsigned u = keymap(X[i]);
  atomicAdd(&hist[((size_t)b << 16) + (u >> 16)], 1u);
}

__global__ __launch_bounds__(1024) void scan16_k(const unsigned* __restrict__ hist,
                                                 RanksArg ra, int2* __restrict__ state){
  __shared__ unsigned csum[1024];
  int b = blockIdx.x, t = threadIdx.x;
  const unsigned* h = hist + ((size_t)b << 16);
  int base = t*64;
  unsigned own = 0;
  for (int j = 0; j < 64; ++j) own += h[base + j];
  csum[t] = own; __syncthreads();
  for (int o = 1; o < 1024; o <<= 1){
    unsigned v = (t >= o) ? csum[t-o] : 0u;
    __syncthreads();
    csum[t] += v;
    __syncthreads();
  }
  unsigned incl = csum[t], excl = incl - own;
  for (int r = 0; r < ra.nr; ++r){
    unsigned rank = (unsigned)ra.r[r];
    if (rank >= excl && rank < incl){
      unsigned rem = rank - excl;
      for (int j = 0; j < 64; ++j){
        unsigned c = h[base + j];
        if (rem < c){ state[b*8 + r] = make_int2(base + j, (int)rem); break; }
        rem -= c;
      }
    }
  }
}

__global__ void histlow_k(const float* __restrict__ X, const int2* __restrict__ state,
                          int nr, unsigned* __restrict__ hist2){
  int i = blockIdx.x*256 + threadIdx.x;
  if (i >= NPIX) return;
  int b = i >> 18;
  unsigned u = keymap(X[i]);
  unsigned top = u >> 16;
  for (int r = 0; r < nr; ++r){
    int2 st = state[b*8 + r];
    if ((unsigned)st.x == top)
      atomicAdd(&hist2[((size_t)(b*6 + r) << 16) + (u & 0xFFFFu)], 1u);
  }
}

__global__ __launch_bounds__(1024) void scanlow_k(const unsigned* __restrict__ hist2,
                                                  const int2* __restrict__ state,
                                                  float* __restrict__ ostat, int nr){
  __shared__ unsigned csum[1024];
  int b = blockIdx.x / nr, r = blockIdx.x % nr, t = threadIdx.x;
  const unsigned* h = hist2 + ((size_t)(b*6 + r) << 16);
  int2 st = state[b*8 + r];
  int base = t*64;
  unsigned own = 0;
  for (int j = 0; j < 64; ++j) own += h[base + j];
  csum[t] = own; __syncthreads();
  for (int o = 1; o < 1024; o <<= 1){
    unsigned v = (t >= o) ? csum[t-o] : 0u;
    __syncthreads();
    csum[t] += v;
    __syncthreads();
  }
  unsigned rank = (unsigned)st.y;
  unsigned incl = csum[t], excl = incl - own;
  if (rank >= excl && rank < incl){
    unsigned rem = rank - excl;
    for (int j = 0; j < 64; ++j){
      unsigned c = h[base + j];
      if (rem < c){
        unsigned key = ((unsigned)st.x << 16) | (unsigned)(base + j);
        ostat[b*8 + r] = invkey(key);
        break;
      }
      rem -= c;
    }
  }
}

__global__ void finq_k(const float* __restrict__ ostat, float* __restrict__ scal,
                       int arrayid, float f0, float f1, float f2){
  int b = threadIdx.x;
  if (b >= BATCH) return;
  const float* o = ostat + b*8;
  if (arrayid == 0){ // image_A: q0.7 -> thr_ir (clipped), q0.97 -> q97A
    float q70 = o[0] + f0*(o[1]-o[0]);
    float q97 = o[2] + f1*(o[3]-o[2]);
    scal[b*8 + S_THR_IR] = fminf(fmaxf(q70, 0.45f), 0.85f);
    scal[b*8 + S_Q97A]   = q97;
  } else if (arrayid == 1){ // image_B: q0.4, q0.85, q0.97
    float q40 = o[0] + f0*(o[1]-o[0]);
    float q85 = o[2] + f1*(o[3]-o[2]);
    float q97 = o[4] + f2*(o[5]-o[4]);
    scal[b*8 + S_THR_VIS] = fminf(fmaxf(q40, 0.3f),  0.7f);
    scal[b*8 + S_THR_SUP] = fminf(fmaxf(q85, 0.75f), 0.98f);
    scal[b*8 + S_Q97B]    = q97;
  } else { // sal: q0.9, q0.97
    float q90 = o[0] + f0*(o[1]-o[0]);
    float q97 = o[2] + f1*(o[3]-o[2]);
    scal[b*8 + S_Q90S] = q90;
    scal[b*8 + S_Q97S] = q97;
  }
}

// ---------- masks ----------
__global__ void mlight_k(const float* __restrict__ A, const float* __restrict__ Bv,
                         const float* __restrict__ sal, const float* __restrict__ scal,
                         unsigned char* __restrict__ ml){
  int i = blockIdx.x*256 + threadIdx.x;
  if (i >= NPIX) return;
  int b = i >> 18;
  float q97s = scal[b*8 + S_Q97S], q97a = scal[b*8 + S_Q97A], q97b = scal[b*8 + S_Q97B];
  ml[i] = (sal[i] > q97s && A[i] > q97a && Bv[i] > q97b) ? 1 : 0;
}

__global__ void scatter_decay_k(const unsigned char* __restrict__ ml, unsigned char* __restrict__ decay){
  int i = blockIdx.x*256 + threadIdx.x;
  if (i >= NPIX || !ml[i]) return;
  int b = i >> 18; int rem = i & (PIX-1);
  int y = rem >> 9, x = rem & (WID-1);
  unsigned char* d = decay + ((size_t)b << 18);
  for (int dy = -50; dy <= 50; ++dy){
    int yy = y + dy;
    if (yy < 0 || yy > HGT-1) continue;
    int d2 = 2500 - dy*dy;
    int w = (int)sqrtf((float)d2);
    while ((w+1)*(w+1) <= d2) ++w;
    while (w*w > d2) --w;
    int xl = x - w; if (xl < 0) xl = 0;
    int xr = x + w; if (xr > WID-1) xr = WID-1;
    unsigned char* row = d + (yy << 9);
    for (int xx = xl; xx <= xr; ++xx) row[xx] = 1;
  }
}

__global__ void bright_rowmax_k(const float* __restrict__ A, const float* __restrict__ scal,
                                float* __restrict__ t1){
  int i = blockIdx.x*256 + threadIdx.x;
  if (i >= NPIX) return;
  int b = i >> 18;
  float thr = scal[b*8 + S_Q97A];
  int x = i & (WID-1); int rb = i - x;
  int lo = x-7; if (lo < 0) lo = 0;
  int hi = x+7; if (hi > WID-1) hi = WID-1;
  float m = 0.f;
  for (int xx = lo; xx <= hi; ++xx) m = fmaxf(m, A[rb+xx] > thr ? 1.f : 0.f);
  t1[i] = m;
}

__global__ void halo_k(const float* __restrict__ t1, const float* __restrict__ A,
                       const float* __restrict__ scal, unsigned char* __restrict__ halo){
  int i = blockIdx.x*256 + threadIdx.x;
  if (i >= NPIX) return;
  int b = i >> 18; int rem = i & (PIX-1);
  int y = rem >> 9, x = rem & (WID-1);
  int lo = y-7; if (lo < 0) lo = 0;
  int hi = y+7; if (hi > HGT-1) hi = HGT-1;
  const float* sp = t1 + ((size_t)b << 18) + x;
  float d = 0.f;
  for (int yy = lo; yy <= hi; ++yy) d = fmaxf(d, sp[yy << 9]);
  float thr = scal[b*8 + S_Q97A];
  halo[i] = (d > 0.5f && !(A[i] > thr)) ? 1 : 0;
}

// ---------- loss_l1 ----------
__global__ void l1_k(const float* __restrict__ A, const float* __restrict__ Bv,
                     const float* __restrict__ F, const float* __restrict__ sal,
                     const float* __restrict__ scal, float* __restrict__ part){
  __shared__ float red[256];
  int i = blockIdx.x*256 + threadIdx.x;
  float s = 0.f;
  if (i < NPIX){
    int b = i >> 18;
    float a = A[i], v = Bv[i], f = F[i];
    float imx = fmaxf(a, v), imn = fminf(a, v);
    float thr_ir = scal[b*8 + S_THR_IR], thr_vis = scal[b*8 + S_THR_VIS];
    float thr_sup = scal[b*8 + S_THR_SUP], q90 = scal[b*8 + S_Q90S];
    float M = 1.f/(1.f + expf(-20.f*(sal[i] - q90)));
    bool irb = a > thr_ir, visb = v > thr_vis, viss = v > thr_sup;
    float salient = visb ? imn : imx;
    if (viss && irb) salient = imx;
    float target = M*salient + (1.f - M)*imx;
    s = fabsf(f - target);
  }
  int t = threadIdx.x;
  red[t] = s; __syncthreads();
  for (int o = 128; o > 0; o >>= 1){ if (t < o) red[t] += red[t+o]; __syncthreads(); }
  if (t == 0) part[blockIdx.x] = red[0];
}

// ---------- loss_grad (sobel) ----------
__device__ __forceinline__ float sobel_at(const float t[34][34], int ly, int lx){
  float gx = (t[ly-1][lx+1] - t[ly-1][lx-1]) + 2.f*(t[ly][lx+1] - t[ly][lx-1])
           + (t[ly+1][lx+1] - t[ly+1][lx-1]);
  float gy = (t[ly-1][lx-1] + 2.f*t[ly-1][lx] + t[ly-1][lx+1])
           - (t[ly+1][lx-1] + 2.f*t[ly+1][lx] + t[ly+1][lx+1]);
  return fabsf(gx) + fabsf(gy);
}

__global__ __launch_bounds__(1024) void grad_k(const float* __restrict__ A, const float* __restrict__ Bv,
                                               const float* __restrict__ F, float* __restrict__ part){
  __shared__ float ta[34][34], tb[34][34], tf[34][34];
  __shared__ float red[1024];
  int b = blockIdx.z;
  int y0 = blockIdx.y*32, x0 = blockIdx.x*32;
  int tid = threadIdx.y*32 + threadIdx.x;
  size_t ib = (size_t)b*PIX;
  for (int idx = tid; idx < 34*34; idx += 1024){
    int ly = idx/34, lx = idx%34;
    int gy = y0 + ly - 1, gx = x0 + lx - 1;
    float a = 0.f, v = 0.f, f = 0.f;
    if (gy >= 0 && gy < HGT && gx >= 0 && gx < WID){
      size_t g = ib + (size_t)gy*WID + gx;
      a = A[g]; v = Bv[g]; f = F[g];
    }
    ta[ly][lx] = a; tb[ly][lx] = v; tf[ly][lx] = f;
  }
  __syncthreads();
  int ly = threadIdx.y + 1, lx = threadIdx.x + 1;
  float ga = sobel_at(ta, ly, lx), gb = sobel_at(tb, ly, lx), gf = sobel_at(tf, ly, lx);
  float val = fabsf(gf - fmaxf(ga, gb));
  red[tid] = val; __syncthreads();
  for (int o = 512; o > 0; o >>= 1){ if (tid < o) red[tid] += red[tid+o]; __syncthreads(); }
  if (tid == 0){
    int blk = (blockIdx.z*gridDim.y + blockIdx.y)*gridDim.x + blockIdx.x;
    part[blk] = red[0];
  }
}

// ---------- SSIM (separable gaussian in LDS) ----------
__global__ __launch_bounds__(1024) void ssim_k(const float* __restrict__ X, const float* __restrict__ F,
                                               float* __restrict__ part, GaussArg gw){
  __shared__ float tx[42][42], tff[42][42];
  __shared__ float hx[42][32], hf[42][32], hxx[42][32], hff[42][32], hxf[42][32];
  __shared__ float red[1024];
  int b = blockIdx.z;
  int y0 = blockIdx.y*32, x0 = blockIdx.x*32;
  int tid = threadIdx.y*32 + threadIdx.x;
  size_t ib = (size_t)b*PIX;
  for (int idx = tid; idx < 42*42; idx += 1024){
    int ly = idx/42, lx = idx%42;
    int gy = y0 + ly - 5, gx = x0 + lx - 5;
    float xv = 0.f, fv = 0.f;
    if (gy >= 0 && gy < HGT && gx >= 0 && gx < WID){
      size_t g = ib + (size_t)gy*WID + gx;
      xv = X[g]; fv = F[g];
    }
    tx[ly][lx] = xv; tff[ly][lx] = fv;
  }
  __syncthreads();
  for (int idx = tid; idx < 42*32; idx += 1024){
    int row = idx/32, col = idx%32;
    float sx=0.f, sf=0.f, sxx=0.f, sff=0.f, sxf=0.f;
    for (int j = 0; j < 11; ++j){
      float g = gw.g[j];
      float xv = tx[row][col+j], fv = tff[row][col+j];
      sx += g*xv; sf += g*fv; sxx += g*xv*xv; sff += g*fv*fv; sxf += g*xv*fv;
    }
    hx[row][col]=sx; hf[row][col]=sf; hxx[row][col]=sxx; hff[row][col]=sff; hxf[row][col]=sxf;
  }
  __syncthreads();
  int ly = threadIdx.y, lx = threadIdx.x;
  float mu1=0.f, mu2=0.f, cxx=0.f, cff=0.f, cxf=0.f;
  for (int j = 0; j < 11; ++j){
    float g = gw.g[j];
    mu1 += g*hx[ly+j][lx]; mu2 += g*hf[ly+j][lx];
    cxx += g*hxx[ly+j][lx]; cff += g*hff[ly+j][lx]; cxf += g*hxf[ly+j][lx];
  }
  float m11 = mu1*mu1, m22 = mu2*mu2, m12 = mu1*mu2;
  float s1 = cxx - m11, s2 = cff - m22, s12 = cxf - m12;
  const float C1 = 1e-4f, C2 = 9e-4f;
  float m = ((2.f*m12 + C1)*(2.f*s12 + C2)) / ((m11 + m22 + C1)*(s1 + s2 + C2));
  red[tid] = m; __syncthreads();
  for (int o = 512; o > 0; o >>= 1){ if (tid < o) red[tid] += red[tid+o]; __syncthreads(); }
  if (tid == 0){
    int blk = (blockIdx.z*gridDim.y + blockIdx.y)*gridDim.x + blockIdx.x;
    part[blk] = red[0];
  }
}

// ---------- box blur 9 + halo/bloom sums ----------
__global__ __launch_bounds__(1024) void hb_k(const float* __restrict__ A, const float* __restrict__ Bv,
                                             const float* __restrict__ F, const float* __restrict__ sal,
                                             const float* __restrict__ scal,
                                             const unsigned char* __restrict__ ml,
                                             const unsigned char* __restrict__ halo,
                                             const unsigned char* __restrict__ decay,
                                             float* __restrict__ p4){
  __shared__ float ti[40][40], tv[40][40], tf[40][40];
  __shared__ float hi_[40][32], hv_[40][32], hf_[40][32];
  __shared__ float red[1024];
  int b = blockIdx.z;
  int y0 = blockIdx.y*32, x0 = blockIdx.x*32;
  int tid = threadIdx.y*32 + threadIdx.x;
  size_t ib = (size_t)b*PIX;
  for (int idx = tid; idx < 40*40; idx += 1024){
    int ly = idx/40, lx = idx%40;
    int gy = y0 + ly - 4, gx = x0 + lx - 4;
    float a = 0.f, v = 0.f, f = 0.f;
    if (gy >= 0 && gy < HGT && gx >= 0 && gx < WID){
      size_t g = ib + (size_t)gy*WID + gx;
      a = A[g]; v = Bv[g]; f = F[g];
    }
    ti[ly][lx] = a; tv[ly][lx] = v; tf[ly][lx] = f;
  }
  __syncthreads();
  for (int idx = tid; idx < 40*32; idx += 1024){
    int row = idx/32, col = idx%32;
    float si=0.f, sv=0.f, sf=0.f;
    for (int j = 0; j < 9; ++j){ si += ti[row][col+j]; sv += tv[row][col+j]; sf += tf[row][col+j]; }
    hi_[row][col]=si; hv_[row][col]=sv; hf_[row][col]=sf;
  }
  __syncthreads();
  int ly = threadIdx.y, lx = threadIdx.x;
  float si=0.f, sv=0.f, sf=0.f;
  for (int j = 0; j < 9; ++j){ si += hi_[ly+j][lx]; sv += hv_[ly+j][lx]; sf += hf_[ly+j][lx]; }
  const float inv81 = 1.f/81.f;
  float ib_ = si*inv81, vb_ = sv*inv81;
  float fb_ = fminf(fmaxf(sf*inv81, 0.f), 1.f);
  int gy = y0 + ly, gx = x0 + lx;
  size_t g = ib + (size_t)gy*WID + gx;
  float q90 = scal[b*8 + S_Q90S];
  float M = 1.f/(1.f + expf(-20.f*(sal[g] - q90)));
  float mh = (halo[g] && !ml[g] && decay[g]) ? 1.f : 0.f;
  float v1 = mh*fmaxf(fb_ - ib_, 0.f);
  float v3 = M*fmaxf(fb_ - vb_, 0.f);

  float vals[4] = {v1, mh, v3, M};
  float sums[4];
  for (int q = 0; q < 4; ++q){
    red[tid] = vals[q]; __syncthreads();
    for (int o = 512; o > 0; o >>= 1){ if (tid < o) red[tid] += red[tid+o]; __syncthreads(); }
    sums[q] = red[0]; __syncthreads();
  }
  if (tid == 0){
    int blk = (blockIdx.z*gridDim.y + blockIdx.y)*gridDim.x + blockIdx.x;
    p4[blk*4+0]=sums[0]; p4[blk*4+1]=sums[1]; p4[blk*4+2]=sums[2]; p4[blk*4+3]=sums[3];
  }
}

// ---------- final reduction ----------
__device__ float blk_sum_1024(float v, float* red){
  int t = threadIdx.x;
  red[t] = v; __syncthreads();
  for (int o = 512; o > 0; o >>= 1){ if (t < o) red[t] += red[t+o]; __syncthreads(); }
  float s = red[0]; __syncthreads();
  return s;
}

__global__ __launch_bounds__(1024) void final_k(const float* __restrict__ pl1, const float* __restrict__ pg,
                                                const float* __restrict__ psa, const float* __restrict__ psb,
                                                const float* __restrict__ p4, float* __restrict__ out){
  __shared__ float red[1024];
  int t = threadIdx.x;
  float v;
  v = 0.f; for (int i = t; i < 4096; i += 1024) v += pl1[i];
  float sumL1 = blk_sum_1024(v, red);
  v = 0.f; for (int i = t; i < 1024; i += 1024) v += pg[i];
  float sumG = blk_sum_1024(v, red);
  v = 0.f; for (int i = t; i < 1024; i += 1024) v += psa[i];
  float sA = blk_sum_1024(v, red);
  v = 0.f; for (int i = t; i < 1024; i += 1024) v += psb[i];
  float sB = blk_sum_1024(v, red);
  float s4[4];
  for (int q = 0; q < 4; ++q){
    v = 0.f; for (int i = t; i < 1024; i += 1024) v += p4[i*4+q];
    s4[q] = blk_sum_1024(v, red);
  }
  if (t == 0){
    const float inv = 1.f/(float)NPIX;
    float loss_l1 = 15.f*sumL1*inv;
    float loss_grad = 14.f*sumG*inv;
    float loss_ssim = 20.f*(1.f - 0.5f*sA*inv - 0.5f*sB*inv);
    float lh = s4[0] / fmaxf(s4[1] + 1e-6f, 1.f);
    float lb = s4[2] / fmaxf(s4[3] + 1e-6f, 1.f);
    float whb = 0.3f*lh + 0.6f*lb;
    out[0] = loss_l1 + loss_grad + loss_ssim + whb;
    out[1] = loss_grad;
    out[2] = loss_l1;
    out[3] = loss_ssim;
    out[4] = whb;
  }
}

// ---------- host ----------
extern "C" void kernel_launch(void* const* d_in, const int* in_sizes, int n_in,
                              void* d_out, int out_size, void* d_ws, size_t ws_size,
                              hipStream_t stream) {
  const float* A  = (const float*)d_in[0];
  const float* Bv = (const float*)d_in[1];
  const float* F  = (const float*)d_in[2];
  float* out = (float*)d_out;
  char* w = (char*)d_ws;

  float* sal = (float*)(w + OFF_SAL);
  float* t1  = (float*)(w + OFF_T1);
  float* t2  = (float*)(w + OFF_T2);
  unsigned char* ml    = (unsigned char*)(w + OFF_ML);
  unsigned char* halo  = (unsigned char*)(w + OFF_HALO);
  unsigned char* decay = (unsigned char*)(w + OFF_DECAY);
  unsigned* h1 = (unsigned*)(w + OFF_H1);
  unsigned* h2 = (unsigned*)(w + OFF_H2);
  int2*  state = (int2*)(w + OFF_STATE);
  float* ostat = (float*)(w + OFF_OSTAT);
  float* scal  = (float*)(w + OFF_SCAL);
  float* pl1 = (float*)(w + OFF_PL1);
  float* pg  = (float*)(w + OFF_PG);
  float* psa = (float*)(w + OFF_PSA);
  float* psb = (float*)(w + OFF_PSB);
  float* p4  = (float*)(w + OFF_P4);

  dim3 b256(256), g4096(NPIX/256);
  dim3 gt(WID/32, HGT/32, BATCH), bt(32, 32);

  // ---- saliency: sal = max_k (A - opening(A,k)), then normalize by per-image mean ----
  const int ks[3] = {9, 15, 31};
  for (int ki = 0; ki < 3; ++ki){
    int r = ks[ki]/2;
    pool_x_k<1><<<g4096, b256, 0, stream>>>(A,  t1, r);
    pool_y_k<1><<<g4096, b256, 0, stream>>>(t1, t2, r);
    pool_x_k<0><<<g4096, b256, 0, stream>>>(t2, t1, r);
    pool_y_k<0><<<g4096, b256, 0, stream>>>(t1, t2, r);
    sal_update_k<<<g4096, b256, 0, stream>>>(sal, A, t2, ki == 0 ? 1 : 0);
  }
  sal_sum_k<<<BATCH, 1024, 0, stream>>>(sal, scal);
  sal_norm_k<<<g4096, b256, 0, stream>>>(sal, scal);

  // ---- quantiles (exact 2-level histogram select) ----
  auto mkrank = [](double q, int* k0, double* fr){
    double pos = q*(double)(PIX-1);
    double fl = floor(pos);
    *k0 = (int)fl; *fr = pos - fl;
  };
  int kA70, kA97, kB40, kB85, kB97, kS90, kS97;
  double fA70, fA97, fB40, fB85, fB97, fS90, fS97;
  mkrank(0.70, &kA70, &fA70); mkrank(0.97, &kA97, &fA97);
  mkrank(0.40, &kB40, &fB40); mkrank(0.85, &kB85, &fB85); mkrank(0.97, &kB97, &fB97);
  mkrank(0.90, &kS90, &fS90); mkrank(0.97, &kS97, &fS97);

  const size_t histBytes = (size_t)BATCH*65536*4 * 7; // h1 + h2 contiguous

  { // image_A
    RanksArg ra{}; ra.r[0]=kA70; ra.r[1]=kA70+1; ra.r[2]=kA97; ra.r[3]=kA97+1; ra.nr=4;
    hipMemsetAsync(w + OFF_H1, 0, histBytes, stream);
    hist16_k<<<g4096, b256, 0, stream>>>(A, h1);
    scan16_k<<<BATCH, 1024, 0, stream>>>(h1, ra, state);
    histlow_k<<<g4096, b256, 0, stream>>>(A, state, ra.nr, h2);
    scanlow_k<<<BATCH*ra.nr, 1024, 0, stream>>>(h2, state, ostat, ra.nr);
    finq_k<<<1, BATCH, 0, stream>>>(ostat, scal, 0, (float)fA70, (float)fA97, 0.f);
  }
  { // image_B
    RanksArg ra{}; ra.r[0]=kB40; ra.r[1]=kB40+1; ra.r[2]=kB85; ra.r[3]=kB85+1; ra.r[4]=kB97; ra.r[5]=kB97+1; ra.nr=6;
    hipMemsetAsync(w + OFF_H1, 0, histBytes, stream);
    hist16_k<<<g4096, b256, 0, stream>>>(Bv, h1);
    scan16_k<<<BATCH, 1024, 0, stream>>>(h1, ra, state);
    histlow_k<<<g4096, b256, 0, stream>>>(Bv, state, ra.nr, h2);
    scanlow_k<<<BATCH*ra.nr, 1024, 0, stream>>>(h2, state, ostat, ra.nr);
    finq_k<<<1, BATCH, 0, stream>>>(ostat, scal, 1, (float)fB40, (float)fB85, (float)fB97);
  }
  { // sal (normalized)
    RanksArg ra{}; ra.r[0]=kS90; ra.r[1]=kS90+1; ra.r[2]=kS97; ra.r[3]=kS97+1; ra.nr=4;
    hipMemsetAsync(w + OFF_H1, 0, histBytes, stream);
    hist16_k<<<g4096, b256, 0, stream>>>(sal, h1);
    scan16_k<<<BATCH, 1024, 0, stream>>>(h1, ra, state);
    histlow_k<<<g4096, b256, 0, stream>>>(sal, state, ra.nr, h2);
    scanlow_k<<<BATCH*ra.nr, 1024, 0, stream>>>(h2, state, ostat, ra.nr);
    finq_k<<<1, BATCH, 0, stream>>>(ostat, scal, 2, (float)fS90, (float)fS97, 0.f);
  }

  // ---- masks: M_light, decay (disk-50 dilation via sparse scatter), halo ----
  mlight_k<<<g4096, b256, 0, stream>>>(A, Bv, sal, scal, ml);
  hipMemsetAsync(w + OFF_DECAY, 0, (size_t)NPIX, stream);
  scatter_decay_k<<<g4096, b256, 0, stream>>>(ml, decay);
  bright_rowmax_k<<<g4096, b256, 0, stream>>>(A, scal, t1);
  halo_k<<<g4096, b256, 0, stream>>>(t1, A, scal, halo);

  // ---- losses ----
  l1_k<<<g4096, b256, 0, stream>>>(A, Bv, F, sal, scal, pl1);
  grad_k<<<gt, bt, 0, stream>>>(A, Bv, F, pg);

  GaussArg ga{};
  {
    double g[11], s = 0.0;
    for (int i = 0; i < 11; ++i){ double d = (double)(i-5); g[i] = exp(-(d*d)/4.5); s += g[i]; }
    for (int i = 0; i < 11; ++i) ga.g[i] = (float)(g[i]/s);
  }
  ssim_k<<<gt, bt, 0, stream>>>(A,  F, psa, ga);
  ssim_k<<<gt, bt, 0, stream>>>(Bv, F, psb, ga);

  hb_k<<<gt, bt, 0, stream>>>(A, Bv, F, sal, scal, ml, halo, decay, p4);

  final_k<<<1, 1024, 0, stream>>>(pl1, pg, psa, psb, p4, out);
}

// Round 2
// 483.000 us; speedup vs baseline: 2.6876x; 2.6876x over previous
//
#include <hip/hip_runtime.h>
#include <cmath>

#define BATCH 4
#define HGT 512
#define WID 512
#define PIX (HGT*WID)        // 262144 = 2^18
#define NPIX (BATCH*PIX)     // 1048576

// ---------- ws layout (bytes) ----------
constexpr size_t OFF_SAL   = 0;                          // NPIX f32
constexpr size_t OFF_T1    = OFF_SAL   + (size_t)NPIX*4;
constexpr size_t OFF_T2    = OFF_T1    + (size_t)NPIX*4;
constexpr size_t OFF_ML    = OFF_T2    + (size_t)NPIX*4; // NPIX u8
constexpr size_t OFF_HALO  = OFF_ML    + (size_t)NPIX;
constexpr size_t OFF_DECAY = OFF_HALO  + (size_t)NPIX;
// quantile select buffers (3-level: 12+12+8 bits)
constexpr size_t OFF_H1    = OFF_DECAY + (size_t)NPIX;                 // 2*BATCH*4096 u32
constexpr size_t OFF_H2    = OFF_H1    + (size_t)2*BATCH*4096*4;       // 10*BATCH*4096 u32
constexpr size_t OFF_H3    = OFF_H2    + (size_t)10*BATCH*4096*4;      // 10*BATCH*256 u32
constexpr size_t OFF_ST1   = OFF_H3    + (size_t)10*BATCH*256*4;       // BATCH*16 int2
constexpr size_t OFF_ST2   = OFF_ST1   + (size_t)BATCH*16*8;
constexpr size_t OFF_OSTAB = OFF_ST2   + (size_t)BATCH*16*8;           // BATCH*16 f32
constexpr size_t OFF_OSTS  = OFF_OSTAB + (size_t)BATCH*16*4;
constexpr size_t OFF_SCAL  = OFF_OSTS  + (size_t)BATCH*16*4;           // BATCH*8 f32
constexpr size_t OFF_SPART = OFF_SCAL  + (size_t)BATCH*8*4;            // BATCH*64 f32
constexpr size_t OFF_PL1   = OFF_SPART + (size_t)BATCH*64*4;           // 4096 f32
constexpr size_t OFF_PG    = OFF_PL1   + 4096*4;                       // 1024 f32
constexpr size_t OFF_PSA   = OFF_PG    + 1024*4;
constexpr size_t OFF_PSB   = OFF_PSA   + 1024*4;
constexpr size_t OFF_P4    = OFF_PSB   + 1024*4;                       // 1024*4 f32

constexpr size_t QHIST_BYTES = (size_t)(2*BATCH*4096 + 10*BATCH*4096 + 10*BATCH*256)*4;

// scalar slots per image (index b*8+slot)
#define S_THR_IR 0
#define S_THR_VIS 1
#define S_THR_SUP 2
#define S_Q97A 3
#define S_Q97B 4
#define S_Q90S 5
#define S_Q97S 6
#define S_SALSUM 7

#define QH_BLOCKS 32

struct QRanks { int rank[10]; int arr[10]; int nr; };
struct GaussArg { float g[11]; };

__device__ __forceinline__ unsigned keymap(float x){
  unsigned u = __float_as_uint(x);
  return (u & 0x80000000u) ? ~u : (u | 0x80000000u);
}
__device__ __forceinline__ float invkey(unsigned k){
  unsigned bits = (k & 0x80000000u) ? (k ^ 0x80000000u) : ~k;
  return __uint_as_float(bits);
}

// ---------- saliency pools (separable, truncated SAME windows) ----------
template<int MIN>
__global__ void pool_x_k(const float* __restrict__ src, float* __restrict__ dst, int r){
  int i = blockIdx.x*256 + threadIdx.x;
  if (i >= NPIX) return;
  int x = i & (WID-1); int rb = i - x;
  int lo = x - r; if (lo < 0) lo = 0;
  int hi = x + r; if (hi > WID-1) hi = WID-1;
  float v = MIN ? 3.4e38f : -3.4e38f;
  for (int xx = lo; xx <= hi; ++xx){
    float s = src[rb + xx];
    v = MIN ? fminf(v, s) : fmaxf(v, s);
  }
  dst[i] = v;
}

template<int MIN>
__global__ void pool_y_k(const float* __restrict__ src, float* __restrict__ dst, int r){
  int i = blockIdx.x*256 + threadIdx.x;
  if (i >= NPIX) return;
  int b = i >> 18; int rem = i & (PIX-1);
  int y = rem >> 9; int x = rem & (WID-1);
  int lo = y - r; if (lo < 0) lo = 0;
  int hi = y + r; if (hi > HGT-1) hi = HGT-1;
  const float* sp = src + ((size_t)b << 18) + x;
  float v = MIN ? 3.4e38f : -3.4e38f;
  for (int yy = lo; yy <= hi; ++yy){
    float s = sp[yy << 9];
    v = MIN ? fminf(v, s) : fmaxf(v, s);
  }
  dst[i] = v;
}

__global__ void sal_update_k(float* __restrict__ sal, const float* __restrict__ A,
                             const float* __restrict__ open_, int first){
  int i = blockIdx.x*256 + threadIdx.x;
  if (i >= NPIX) return;
  float s = A[i] - open_[i];
  sal[i] = first ? s : fmaxf(sal[i], s);
}

// parallel per-image sum: 64 blocks/image -> partials -> wave combine
__global__ void salpart_k(const float* __restrict__ sal, float* __restrict__ part){
  __shared__ float red[256];
  int b = blockIdx.y;
  const float* sp = sal + (size_t)b*PIX;
  float s = 0.f;
  for (int i = blockIdx.x*256 + threadIdx.x; i < PIX; i += 64*256) s += sp[i];
  int t = threadIdx.x;
  red[t] = s; __syncthreads();
  for (int o = 128; o > 0; o >>= 1){ if (t < o) red[t] += red[t+o]; __syncthreads(); }
  if (t == 0) part[b*64 + blockIdx.x] = red[0];
}

__global__ void salfin_k(const float* __restrict__ part, float* __restrict__ scal){
  int t = threadIdx.x;          // 256 threads: 4 waves, one per image
  int b = t >> 6, lane = t & 63;
  float v = part[b*64 + lane];
  for (int o = 32; o > 0; o >>= 1) v += __shfl_down(v, o);
  if (lane == 0) scal[b*8 + S_SALSUM] = v;
}

__global__ void sal_norm_k(float* __restrict__ sal, const float* __restrict__ scal){
  int i = blockIdx.x*256 + threadIdx.x;
  if (i >= NPIX) return;
  int b = i >> 18;
  float mean = scal[b*8 + S_SALSUM] * (1.0f/(float)PIX);
  sal[i] = sal[i] / (mean + 1e-6f);
}

// ---------- exact quantile: three-level (12/12/8-bit) LDS-privatized select ----------
// L1: hist of key>>20 (4096 bins) per (arr,b)
__global__ __launch_bounds__(256) void qh1_k(const float* __restrict__ X0, const float* __restrict__ X1,
                                             unsigned* __restrict__ h1){
  __shared__ unsigned hist[4096];
  int b = blockIdx.y, z = blockIdx.z;
  const float* p = (z ? X1 : X0) + (size_t)b*PIX;
  for (int i = threadIdx.x; i < 4096; i += 256) hist[i] = 0;
  __syncthreads();
  for (int i = blockIdx.x*256 + threadIdx.x; i < PIX; i += QH_BLOCKS*256){
    unsigned k = keymap(p[i]);
    atomicAdd(&hist[k >> 20], 1u);
  }
  __syncthreads();
  unsigned* g = h1 + ((size_t)(z*BATCH + b))*4096;
  for (int i = threadIdx.x; i < 4096; i += 256){
    unsigned c = hist[i];
    if (c) atomicAdd(&g[i], c);
  }
}

// L1 scan: block per (z,b); locate bin+remainder for each rank of array z
__global__ __launch_bounds__(1024) void qs1_k(const unsigned* __restrict__ h1, QRanks ra,
                                              int2* __restrict__ st1){
  __shared__ unsigned csum[1024];
  int zb = blockIdx.x; int z = zb / BATCH, b = zb % BATCH;
  const unsigned* h = h1 + (size_t)zb*4096;
  int t = threadIdx.x, base = t*4;
  unsigned c4[4]; unsigned own = 0;
  for (int j = 0; j < 4; ++j){ c4[j] = h[base+j]; own += c4[j]; }
  csum[t] = own; __syncthreads();
  for (int o = 1; o < 1024; o <<= 1){
    unsigned v = (t >= o) ? csum[t-o] : 0u;
    __syncthreads();
    csum[t] += v;
    __syncthreads();
  }
  unsigned incl = csum[t], excl = incl - own;
  for (int r = 0; r < ra.nr; ++r){
    if (ra.arr[r] != z) continue;
    unsigned rank = (unsigned)ra.rank[r];
    if (rank >= excl && rank < incl){
      unsigned rem = rank - excl;
      for (int j = 0; j < 4; ++j){
        if (rem < c4[j]){ st1[b*16 + r] = make_int2(base + j, (int)rem); break; }
        rem -= c4[j];
      }
    }
  }
}

// L2: hist of (key>>8)&0xFFF restricted to rank's L1 bin; block per (blk,b,r)
__global__ __launch_bounds__(256) void qh2_k(const float* __restrict__ X0, const float* __restrict__ X1,
                                             const int2* __restrict__ st1, QRanks ra,
                                             unsigned* __restrict__ h2){
  __shared__ unsigned hist[4096];
  int b = blockIdx.y, r = blockIdx.z;
  int z = ra.arr[r];
  unsigned bin1 = (unsigned)st1[b*16 + r].x;
  const float* p = (z ? X1 : X0) + (size_t)b*PIX;
  for (int i = threadIdx.x; i < 4096; i += 256) hist[i] = 0;
  __syncthreads();
  for (int i = blockIdx.x*256 + threadIdx.x; i < PIX; i += QH_BLOCKS*256){
    unsigned k = keymap(p[i]);
    if ((k >> 20) == bin1) atomicAdd(&hist[(k >> 8) & 0xFFFu], 1u);
  }
  __syncthreads();
  unsigned* g = h2 + ((size_t)(r*BATCH + b))*4096;
  for (int i = threadIdx.x; i < 4096; i += 256){
    unsigned c = hist[i];
    if (c) atomicAdd(&g[i], c);
  }
}

__global__ __launch_bounds__(1024) void qs2_k(const unsigned* __restrict__ h2,
                                              const int2* __restrict__ st1, QRanks ra,
                                              int2* __restrict__ st2){
  __shared__ unsigned csum[1024];
  int rb = blockIdx.x; int r = rb / BATCH, b = rb % BATCH;
  const unsigned* h = h2 + (size_t)rb*4096;
  int t = threadIdx.x, base = t*4;
  unsigned c4[4]; unsigned own = 0;
  for (int j = 0; j < 4; ++j){ c4[j] = h[base+j]; own += c4[j]; }
  csum[t] = own; __syncthreads();
  for (int o = 1; o < 1024; o <<= 1){
    unsigned v = (t >= o) ? csum[t-o] : 0u;
    __syncthreads();
    csum[t] += v;
    __syncthreads();
  }
  unsigned rank = (unsigned)st1[b*16 + r].y;
  unsigned incl = csum[t], excl = incl - own;
  if (rank >= excl && rank < incl){
    unsigned rem = rank - excl;
    for (int j = 0; j < 4; ++j){
      if (rem < c4[j]){ st2[b*16 + r] = make_int2(base + j, (int)rem); break; }
      rem -= c4[j];
    }
  }
}

// L3: hist of key&0xFF restricted to rank's top-24; then scan -> exact value
__global__ __launch_bounds__(256) void qh3_k(const float* __restrict__ X0, const float* __restrict__ X1,
                                             const int2* __restrict__ st1, const int2* __restrict__ st2,
                                             QRanks ra, unsigned* __restrict__ h3){
  __shared__ unsigned hist[256];
  int b = blockIdx.y, r = blockIdx.z;
  int z = ra.arr[r];
  unsigned top24 = ((unsigned)st1[b*16 + r].x << 12) | (unsigned)st2[b*16 + r].x;
  const float* p = (z ? X1 : X0) + (size_t)b*PIX;
  if (threadIdx.x < 256) hist[threadIdx.x] = 0;
  __syncthreads();
  for (int i = blockIdx.x*256 + threadIdx.x; i < PIX; i += QH_BLOCKS*256){
    unsigned k = keymap(p[i]);
    if ((k >> 8) == top24) atomicAdd(&hist[k & 0xFFu], 1u);
  }
  __syncthreads();
  unsigned* g = h3 + ((size_t)(r*BATCH + b))*256;
  unsigned c = hist[threadIdx.x];
  if (c) atomicAdd(&g[threadIdx.x], c);
}

__global__ __launch_bounds__(256) void qs3_k(const unsigned* __restrict__ h3,
                                             const int2* __restrict__ st1, const int2* __restrict__ st2,
                                             float* __restrict__ ostat){
  __shared__ unsigned csum[256];
  int rb = blockIdx.x; int r = rb / BATCH, b = rb % BATCH;
  const unsigned* h = h3 + (size_t)rb*256;
  int t = threadIdx.x;
  unsigned own = h[t];
  csum[t] = own; __syncthreads();
  for (int o = 1; o < 256; o <<= 1){
    unsigned v = (t >= o) ? csum[t-o] : 0u;
    __syncthreads();
    csum[t] += v;
    __syncthreads();
  }
  unsigned rank = (unsigned)st2[b*16 + r].y;
  unsigned incl = csum[t], excl = incl - own;
  if (rank >= excl && rank < incl){
    unsigned key = (((unsigned)st1[b*16 + r].x) << 20) | (((unsigned)st2[b*16 + r].x) << 8) | (unsigned)t;
    ostat[b*16 + r] = invkey(key);
  }
}

__global__ void finqAB_k(const float* __restrict__ ostat, float* __restrict__ scal,
                         float fA70, float fA97, float fB40, float fB85, float fB97){
  int b = threadIdx.x;
  if (b >= BATCH) return;
  const float* o = ostat + b*16;
  float q70  = o[0] + fA70*(o[1]-o[0]);
  float q97a = o[2] + fA97*(o[3]-o[2]);
  float q40  = o[4] + fB40*(o[5]-o[4]);
  float q85  = o[6] + fB85*(o[7]-o[6]);
  float q97b = o[8] + fB97*(o[9]-o[8]);
  scal[b*8 + S_THR_IR]  = fminf(fmaxf(q70, 0.45f), 0.85f);
  scal[b*8 + S_Q97A]    = q97a;
  scal[b*8 + S_THR_VIS] = fminf(fmaxf(q40, 0.3f),  0.7f);
  scal[b*8 + S_THR_SUP] = fminf(fmaxf(q85, 0.75f), 0.98f);
  scal[b*8 + S_Q97B]    = q97b;
}

__global__ void finqS_k(const float* __restrict__ ostat, float* __restrict__ scal,
                        float f90, float f97){
  int b = threadIdx.x;
  if (b >= BATCH) return;
  const float* o = ostat + b*16;
  scal[b*8 + S_Q90S] = o[0] + f90*(o[1]-o[0]);
  scal[b*8 + S_Q97S] = o[2] + f97*(o[3]-o[2]);
}

// ---------- masks ----------
__global__ void mlight_k(const float* __restrict__ A, const float* __restrict__ Bv,
                         const float* __restrict__ sal, const float* __restrict__ scal,
                         unsigned char* __restrict__ ml){
  int i = blockIdx.x*256 + threadIdx.x;
  if (i >= NPIX) return;
  int b = i >> 18;
  float q97s = scal[b*8 + S_Q97S], q97a = scal[b*8 + S_Q97A], q97b = scal[b*8 + S_Q97B];
  ml[i] = (sal[i] > q97s && A[i] > q97a && Bv[i] > q97b) ? 1 : 0;
}

__global__ void scatter_decay_k(const unsigned char* __restrict__ ml, unsigned char* __restrict__ decay){
  int i = blockIdx.x*256 + threadIdx.x;
  if (i >= NPIX || !ml[i]) return;
  int b = i >> 18; int rem = i & (PIX-1);
  int y = rem >> 9, x = rem & (WID-1);
  unsigned char* d = decay + ((size_t)b << 18);
  for (int dy = -50; dy <= 50; ++dy){
    int yy = y + dy;
    if (yy < 0 || yy > HGT-1) continue;
    int d2 = 2500 - dy*dy;
    int w = (int)sqrtf((float)d2);
    while ((w+1)*(w+1) <= d2) ++w;
    while (w*w > d2) --w;
    int xl = x - w; if (xl < 0) xl = 0;
    int xr = x + w; if (xr > WID-1) xr = WID-1;
    unsigned char* row = d + (yy << 9);
    for (int xx = xl; xx <= xr; ++xx) row[xx] = 1;
  }
}

__global__ void bright_rowmax_k(const float* __restrict__ A, const float* __restrict__ scal,
                                float* __restrict__ t1){
  int i = blockIdx.x*256 + threadIdx.x;
  if (i >= NPIX) return;
  int b = i >> 18;
  float thr = scal[b*8 + S_Q97A];
  int x = i & (WID-1); int rb = i - x;
  int lo = x-7; if (lo < 0) lo = 0;
  int hi = x+7; if (hi > WID-1) hi = WID-1;
  float m = 0.f;
  for (int xx = lo; xx <= hi; ++xx) m = fmaxf(m, A[rb+xx] > thr ? 1.f : 0.f);
  t1[i] = m;
}

__global__ void halo_k(const float* __restrict__ t1, const float* __restrict__ A,
                       const float* __restrict__ scal, unsigned char* __restrict__ halo){
  int i = blockIdx.x*256 + threadIdx.x;
  if (i >= NPIX) return;
  int b = i >> 18; int rem = i & (PIX-1);
  int y = rem >> 9, x = rem & (WID-1);
  int lo = y-7; if (lo < 0) lo = 0;
  int hi = y+7; if (hi > HGT-1) hi = HGT-1;
  const float* sp = t1 + ((size_t)b << 18) + x;
  float d = 0.f;
  for (int yy = lo; yy <= hi; ++yy) d = fmaxf(d, sp[yy << 9]);
  float thr = scal[b*8 + S_Q97A];
  halo[i] = (d > 0.5f && !(A[i] > thr)) ? 1 : 0;
}

// ---------- loss_l1 ----------
__global__ void l1_k(const float* __restrict__ A, const float* __restrict__ Bv,
                     const float* __restrict__ F, const float* __restrict__ sal,
                     const float* __restrict__ scal, float* __restrict__ part){
  __shared__ float red[256];
  int i = blockIdx.x*256 + threadIdx.x;
  float s = 0.f;
  if (i < NPIX){
    int b = i >> 18;
    float a = A[i], v = Bv[i], f = F[i];
    float imx = fmaxf(a, v), imn = fminf(a, v);
    float thr_ir = scal[b*8 + S_THR_IR], thr_vis = scal[b*8 + S_THR_VIS];
    float thr_sup = scal[b*8 + S_THR_SUP], q90 = scal[b*8 + S_Q90S];
    float M = 1.f/(1.f + expf(-20.f*(sal[i] - q90)));
    bool irb = a > thr_ir, visb = v > thr_vis, viss = v > thr_sup;
    float salient = visb ? imn : imx;
    if (viss && irb) salient = imx;
    float target = M*salient + (1.f - M)*imx;
    s = fabsf(f - target);
  }
  int t = threadIdx.x;
  red[t] = s; __syncthreads();
  for (int o = 128; o > 0; o >>= 1){ if (t < o) red[t] += red[t+o]; __syncthreads(); }
  if (t == 0) part[blockIdx.x] = red[0];
}

// ---------- loss_grad (sobel) ----------
__device__ __forceinline__ float sobel_at(const float t[34][34], int ly, int lx){
  float gx = (t[ly-1][lx+1] - t[ly-1][lx-1]) + 2.f*(t[ly][lx+1] - t[ly][lx-1])
           + (t[ly+1][lx+1] - t[ly+1][lx-1]);
  float gy = (t[ly-1][lx-1] + 2.f*t[ly-1][lx] + t[ly-1][lx+1])
           - (t[ly+1][lx-1] + 2.f*t[ly+1][lx] + t[ly+1][lx+1]);
  return fabsf(gx) + fabsf(gy);
}

__global__ __launch_bounds__(1024) void grad_k(const float* __restrict__ A, const float* __restrict__ Bv,
                                               const float* __restrict__ F, float* __restrict__ part){
  __shared__ float ta[34][34], tb[34][34], tf[34][34];
  __shared__ float red[1024];
  int b = blockIdx.z;
  int y0 = blockIdx.y*32, x0 = blockIdx.x*32;
  int tid = threadIdx.y*32 + threadIdx.x;
  size_t ib = (size_t)b*PIX;
  for (int idx = tid; idx < 34*34; idx += 1024){
    int ly = idx/34, lx = idx%34;
    int gy = y0 + ly - 1, gx = x0 + lx - 1;
    float a = 0.f, v = 0.f, f = 0.f;
    if (gy >= 0 && gy < HGT && gx >= 0 && gx < WID){
      size_t g = ib + (size_t)gy*WID + gx;
      a = A[g]; v = Bv[g]; f = F[g];
    }
    ta[ly][lx] = a; tb[ly][lx] = v; tf[ly][lx] = f;
  }
  __syncthreads();
  int ly = threadIdx.y + 1, lx = threadIdx.x + 1;
  float ga = sobel_at(ta, ly, lx), gb = sobel_at(tb, ly, lx), gf = sobel_at(tf, ly, lx);
  float val = fabsf(gf - fmaxf(ga, gb));
  red[tid] = val; __syncthreads();
  for (int o = 512; o > 0; o >>= 1){ if (tid < o) red[tid] += red[tid+o]; __syncthreads(); }
  if (tid == 0){
    int blk = (blockIdx.z*gridDim.y + blockIdx.y)*gridDim.x + blockIdx.x;
    part[blk] = red[0];
  }
}

// ---------- SSIM (separable gaussian in LDS) ----------
__global__ __launch_bounds__(1024) void ssim_k(const float* __restrict__ X, const float* __restrict__ F,
                                               float* __restrict__ part, GaussArg gw){
  __shared__ float tx[42][42], tff[42][42];
  __shared__ float hx[42][32], hf[42][32], hxx[42][32], hff[42][32], hxf[42][32];
  __shared__ float red[1024];
  int b = blockIdx.z;
  int y0 = blockIdx.y*32, x0 = blockIdx.x*32;
  int tid = threadIdx.y*32 + threadIdx.x;
  size_t ib = (size_t)b*PIX;
  for (int idx = tid; idx < 42*42; idx += 1024){
    int ly = idx/42, lx = idx%42;
    int gy = y0 + ly - 5, gx = x0 + lx - 5;
    float xv = 0.f, fv = 0.f;
    if (gy >= 0 && gy < HGT && gx >= 0 && gx < WID){
      size_t g = ib + (size_t)gy*WID + gx;
      xv = X[g]; fv = F[g];
    }
    tx[ly][lx] = xv; tff[ly][lx] = fv;
  }
  __syncthreads();
  for (int idx = tid; idx < 42*32; idx += 1024){
    int row = idx/32, col = idx%32;
    float sx=0.f, sf=0.f, sxx=0.f, sff=0.f, sxf=0.f;
    for (int j = 0; j < 11; ++j){
      float g = gw.g[j];
      float xv = tx[row][col+j], fv = tff[row][col+j];
      sx += g*xv; sf += g*fv; sxx += g*xv*xv; sff += g*fv*fv; sxf += g*xv*fv;
    }
    hx[row][col]=sx; hf[row][col]=sf; hxx[row][col]=sxx; hff[row][col]=sff; hxf[row][col]=sxf;
  }
  __syncthreads();
  int ly = threadIdx.y, lx = threadIdx.x;
  float mu1=0.f, mu2=0.f, cxx=0.f, cff=0.f, cxf=0.f;
  for (int j = 0; j < 11; ++j){
    float g = gw.g[j];
    mu1 += g*hx[ly+j][lx]; mu2 += g*hf[ly+j][lx];
    cxx += g*hxx[ly+j][lx]; cff += g*hff[ly+j][lx]; cxf += g*hxf[ly+j][lx];
  }
  float m11 = mu1*mu1, m22 = mu2*mu2, m12 = mu1*mu2;
  float s1 = cxx - m11, s2 = cff - m22, s12 = cxf - m12;
  const float C1 = 1e-4f, C2 = 9e-4f;
  float m = ((2.f*m12 + C1)*(2.f*s12 + C2)) / ((m11 + m22 + C1)*(s1 + s2 + C2));
  red[tid] = m; __syncthreads();
  for (int o = 512; o > 0; o >>= 1){ if (tid < o) red[tid] += red[tid+o]; __syncthreads(); }
  if (tid == 0){
    int blk = (blockIdx.z*gridDim.y + blockIdx.y)*gridDim.x + blockIdx.x;
    part[blk] = red[0];
  }
}

// ---------- box blur 9 + halo/bloom sums ----------
__global__ __launch_bounds__(1024) void hb_k(const float* __restrict__ A, const float* __restrict__ Bv,
                                             const float* __restrict__ F, const float* __restrict__ sal,
                                             const float* __restrict__ scal,
                                             const unsigned char* __restrict__ ml,
                                             const unsigned char* __restrict__ halo,
                                             const unsigned char* __restrict__ decay,
                                             float* __restrict__ p4){
  __shared__ float ti[40][40], tv[40][40], tf[40][40];
  __shared__ float hi_[40][32], hv_[40][32], hf_[40][32];
  __shared__ float red[1024];
  int b = blockIdx.z;
  int y0 = blockIdx.y*32, x0 = blockIdx.x*32;
  int tid = threadIdx.y*32 + threadIdx.x;
  size_t ib = (size_t)b*PIX;
  for (int idx = tid; idx < 40*40; idx += 1024){
    int ly = idx/40, lx = idx%40;
    int gy = y0 + ly - 4, gx = x0 + lx - 4;
    float a = 0.f, v = 0.f, f = 0.f;
    if (gy >= 0 && gy < HGT && gx >= 0 && gx < WID){
      size_t g = ib + (size_t)gy*WID + gx;
      a = A[g]; v = Bv[g]; f = F[g];
    }
    ti[ly][lx] = a; tv[ly][lx] = v; tf[ly][lx] = f;
  }
  __syncthreads();
  for (int idx = tid; idx < 40*32; idx += 1024){
    int row = idx/32, col = idx%32;
    float si=0.f, sv=0.f, sf=0.f;
    for (int j = 0; j < 9; ++j){ si += ti[row][col+j]; sv += tv[row][col+j]; sf += tf[row][col+j]; }
    hi_[row][col]=si; hv_[row][col]=sv; hf_[row][col]=sf;
  }
  __syncthreads();
  int ly = threadIdx.y, lx = threadIdx.x;
  float si=0.f, sv=0.f, sf=0.f;
  for (int j = 0; j < 9; ++j){ si += hi_[ly+j][lx]; sv += hv_[ly+j][lx]; sf += hf_[ly+j][lx]; }
  const float inv81 = 1.f/81.f;
  float ib_ = si*inv81, vb_ = sv*inv81;
  float fb_ = fminf(fmaxf(sf*inv81, 0.f), 1.f);
  int gy = y0 + ly, gx = x0 + lx;
  size_t g = ib + (size_t)gy*WID + gx;
  float q90 = scal[b*8 + S_Q90S];
  float M = 1.f/(1.f + expf(-20.f*(sal[g] - q90)));
  float mh = (halo[g] && !ml[g] && decay[g]) ? 1.f : 0.f;
  float v1 = mh*fmaxf(fb_ - ib_, 0.f);
  float v3 = M*fmaxf(fb_ - vb_, 0.f);

  float vals[4] = {v1, mh, v3, M};
  float sums[4];
  for (int q = 0; q < 4; ++q){
    red[tid] = vals[q]; __syncthreads();
    for (int o = 512; o > 0; o >>= 1){ if (tid < o) red[tid] += red[tid+o]; __syncthreads(); }
    sums[q] = red[0]; __syncthreads();
  }
  if (tid == 0){
    int blk = (blockIdx.z*gridDim.y + blockIdx.y)*gridDim.x + blockIdx.x;
    p4[blk*4+0]=sums[0]; p4[blk*4+1]=sums[1]; p4[blk*4+2]=sums[2]; p4[blk*4+3]=sums[3];
  }
}

// ---------- final reduction ----------
__device__ float blk_sum_1024(float v, float* red){
  int t = threadIdx.x;
  red[t] = v; __syncthreads();
  for (int o = 512; o > 0; o >>= 1){ if (t < o) red[t] += red[t+o]; __syncthreads(); }
  float s = red[0]; __syncthreads();
  return s;
}

__global__ __launch_bounds__(1024) void final_k(const float* __restrict__ pl1, const float* __restrict__ pg,
                                                const float* __restrict__ psa, const float* __restrict__ psb,
                                                const float* __restrict__ p4, float* __restrict__ out){
  __shared__ float red[1024];
  int t = threadIdx.x;
  float v;
  v = 0.f; for (int i = t; i < 4096; i += 1024) v += pl1[i];
  float sumL1 = blk_sum_1024(v, red);
  v = 0.f; for (int i = t; i < 1024; i += 1024) v += pg[i];
  float sumG = blk_sum_1024(v, red);
  v = 0.f; for (int i = t; i < 1024; i += 1024) v += psa[i];
  float sA = blk_sum_1024(v, red);
  v = 0.f; for (int i = t; i < 1024; i += 1024) v += psb[i];
  float sB = blk_sum_1024(v, red);
  float s4[4];
  for (int q = 0; q < 4; ++q){
    v = 0.f; for (int i = t; i < 1024; i += 1024) v += p4[i*4+q];
    s4[q] = blk_sum_1024(v, red);
  }
  if (t == 0){
    const float inv = 1.f/(float)NPIX;
    float loss_l1 = 15.f*sumL1*inv;
    float loss_grad = 14.f*sumG*inv;
    float loss_ssim = 20.f*(1.f - 0.5f*sA*inv - 0.5f*sB*inv);
    float lh = s4[0] / fmaxf(s4[1] + 1e-6f, 1.f);
    float lb = s4[2] / fmaxf(s4[3] + 1e-6f, 1.f);
    float whb = 0.3f*lh + 0.6f*lb;
    out[0] = loss_l1 + loss_grad + loss_ssim + whb;
    out[1] = loss_grad;
    out[2] = loss_l1;
    out[3] = loss_ssim;
    out[4] = whb;
  }
}

// ---------- host ----------
extern "C" void kernel_launch(void* const* d_in, const int* in_sizes, int n_in,
                              void* d_out, int out_size, void* d_ws, size_t ws_size,
                              hipStream_t stream) {
  const float* A  = (const float*)d_in[0];
  const float* Bv = (const float*)d_in[1];
  const float* F  = (const float*)d_in[2];
  float* out = (float*)d_out;
  char* w = (char*)d_ws;

  float* sal = (float*)(w + OFF_SAL);
  float* t1  = (float*)(w + OFF_T1);
  float* t2  = (float*)(w + OFF_T2);
  unsigned char* ml    = (unsigned char*)(w + OFF_ML);
  unsigned char* halo  = (unsigned char*)(w + OFF_HALO);
  unsigned char* decay = (unsigned char*)(w + OFF_DECAY);
  unsigned* h1 = (unsigned*)(w + OFF_H1);
  unsigned* h2 = (unsigned*)(w + OFF_H2);
  unsigned* h3 = (unsigned*)(w + OFF_H3);
  int2* st1 = (int2*)(w + OFF_ST1);
  int2* st2 = (int2*)(w + OFF_ST2);
  float* ostAB = (float*)(w + OFF_OSTAB);
  float* ostS  = (float*)(w + OFF_OSTS);
  float* scal  = (float*)(w + OFF_SCAL);
  float* spart = (float*)(w + OFF_SPART);
  float* pl1 = (float*)(w + OFF_PL1);
  float* pg  = (float*)(w + OFF_PG);
  float* psa = (float*)(w + OFF_PSA);
  float* psb = (float*)(w + OFF_PSB);
  float* p4  = (float*)(w + OFF_P4);

  dim3 b256(256), g4096(NPIX/256);
  dim3 gt(WID/32, HGT/32, BATCH), bt(32, 32);

  // ---- rank positions (exact order statistics k, k+1 + fraction) ----
  auto mkrank = [](double q, int* k0, double* fr){
    double pos = q*(double)(PIX-1);
    double fl = floor(pos);
    *k0 = (int)fl; *fr = pos - fl;
  };
  int kA70, kA97, kB40, kB85, kB97, kS90, kS97;
  double fA70, fA97, fB40, fB85, fB97, fS90, fS97;
  mkrank(0.70, &kA70, &fA70); mkrank(0.97, &kA97, &fA97);
  mkrank(0.40, &kB40, &fB40); mkrank(0.85, &kB85, &fB85); mkrank(0.97, &kB97, &fB97);
  mkrank(0.90, &kS90, &fS90); mkrank(0.97, &kS97, &fS97);

  // ---- A+B quantiles (independent of saliency; issue first) ----
  {
    QRanks ra{};
    int rr[10]  = {kA70, kA70+1, kA97, kA97+1, kB40, kB40+1, kB85, kB85+1, kB97, kB97+1};
    int aa[10]  = {0,0,0,0, 1,1,1,1,1,1};
    for (int i = 0; i < 10; ++i){ ra.rank[i]=rr[i]; ra.arr[i]=aa[i]; }
    ra.nr = 10;
    hipMemsetAsync(w + OFF_H1, 0, QHIST_BYTES, stream);
    qh1_k<<<dim3(QH_BLOCKS, BATCH, 2), b256, 0, stream>>>(A, Bv, h1);
    qs1_k<<<2*BATCH, 1024, 0, stream>>>(h1, ra, st1);
    qh2_k<<<dim3(QH_BLOCKS, BATCH, 10), b256, 0, stream>>>(A, Bv, st1, ra, h2);
    qs2_k<<<10*BATCH, 1024, 0, stream>>>(h2, st1, ra, st2);
    qh3_k<<<dim3(QH_BLOCKS, BATCH, 10), b256, 0, stream>>>(A, Bv, st1, st2, ra, h3);
    qs3_k<<<10*BATCH, 256, 0, stream>>>(h3, st1, st2, ostAB);
    finqAB_k<<<1, BATCH, 0, stream>>>(ostAB, scal, (float)fA70, (float)fA97,
                                      (float)fB40, (float)fB85, (float)fB97);
  }

  // ---- saliency: sal = max_k (A - opening(A,k)), then normalize by per-image mean ----
  const int ks[3] = {9, 15, 31};
  for (int ki = 0; ki < 3; ++ki){
    int r = ks[ki]/2;
    pool_x_k<1><<<g4096, b256, 0, stream>>>(A,  t1, r);
    pool_y_k<1><<<g4096, b256, 0, stream>>>(t1, t2, r);
    pool_x_k<0><<<g4096, b256, 0, stream>>>(t2, t1, r);
    pool_y_k<0><<<g4096, b256, 0, stream>>>(t1, t2, r);
    sal_update_k<<<g4096, b256, 0, stream>>>(sal, A, t2, ki == 0 ? 1 : 0);
  }
  salpart_k<<<dim3(64, BATCH), b256, 0, stream>>>(sal, spart);
  salfin_k<<<1, 256, 0, stream>>>(spart, scal);
  sal_norm_k<<<g4096, b256, 0, stream>>>(sal, scal);

  // ---- sal quantiles ----
  {
    QRanks ra{};
    int rr[4] = {kS90, kS90+1, kS97, kS97+1};
    for (int i = 0; i < 4; ++i){ ra.rank[i]=rr[i]; ra.arr[i]=0; }
    ra.nr = 4;
    hipMemsetAsync(w + OFF_H1, 0, QHIST_BYTES, stream);
    qh1_k<<<dim3(QH_BLOCKS, BATCH, 1), b256, 0, stream>>>(sal, sal, h1);
    qs1_k<<<1*BATCH, 1024, 0, stream>>>(h1, ra, st1);
    qh2_k<<<dim3(QH_BLOCKS, BATCH, 4), b256, 0, stream>>>(sal, sal, st1, ra, h2);
    qs2_k<<<4*BATCH, 1024, 0, stream>>>(h2, st1, ra, st2);
    qh3_k<<<dim3(QH_BLOCKS, BATCH, 4), b256, 0, stream>>>(sal, sal, st1, st2, ra, h3);
    qs3_k<<<4*BATCH, 256, 0, stream>>>(h3, st1, st2, ostS);
    finqS_k<<<1, BATCH, 0, stream>>>(ostS, scal, (float)fS90, (float)fS97);
  }

  // ---- masks: M_light, decay (disk-50 dilation via sparse scatter), halo ----
  mlight_k<<<g4096, b256, 0, stream>>>(A, Bv, sal, scal, ml);
  hipMemsetAsync(w + OFF_DECAY, 0, (size_t)NPIX, stream);
  scatter_decay_k<<<g4096, b256, 0, stream>>>(ml, decay);
  bright_rowmax_k<<<g4096, b256, 0, stream>>>(A, scal, t1);
  halo_k<<<g4096, b256, 0, stream>>>(t1, A, scal, halo);

  // ---- losses ----
  l1_k<<<g4096, b256, 0, stream>>>(A, Bv, F, sal, scal, pl1);
  grad_k<<<gt, bt, 0, stream>>>(A, Bv, F, pg);

  GaussArg ga{};
  {
    double g[11], s = 0.0;
    for (int i = 0; i < 11; ++i){ double d = (double)(i-5); g[i] = exp(-(d*d)/4.5); s += g[i]; }
    for (int i = 0; i < 11; ++i) ga.g[i] = (float)(g[i]/s);
  }
  ssim_k<<<gt, bt, 0, stream>>>(A,  F, psa, ga);
  ssim_k<<<gt, bt, 0, stream>>>(Bv, F, psb, ga);

  hb_k<<<gt, bt, 0, stream>>>(A, Bv, F, sal, scal, ml, halo, decay, p4);

  final_k<<<1, 1024, 0, stream>>>(pl1, pg, psa, psb, p4, out);
}

// Round 3
// 355.944 us; speedup vs baseline: 3.6470x; 1.3570x over previous
//
#include <hip/hip_runtime.h>
#include <cmath>

#define BATCH 4
#define HGT 512
#define WID 512
#define PIX (HGT*WID)        // 262144 = 2^18
#define NPIX (BATCH*PIX)     // 1048576

// ---------- ws layout (bytes) ----------
constexpr size_t OFF_SAL   = 0;                          // NPIX f32
constexpr size_t OFF_T1    = OFF_SAL   + (size_t)NPIX*4;
constexpr size_t OFF_T2    = OFF_T1    + (size_t)NPIX*4;
constexpr size_t OFF_ML    = OFF_T2    + (size_t)NPIX*4; // NPIX u8
constexpr size_t OFF_HALO  = OFF_ML    + (size_t)NPIX;
constexpr size_t OFF_DECAY = OFF_HALO  + (size_t)NPIX;
// point list for sparse disk paint
constexpr size_t OFF_CNT   = OFF_DECAY + (size_t)NPIX;                 // BATCH i32
constexpr size_t OFF_PTS   = OFF_CNT   + 64;                           // NPIX i32 (worst case)
// quantile select buffers (3-level: 12+12+8 bits)
constexpr size_t OFF_H1    = OFF_PTS   + (size_t)NPIX*4;               // 2*BATCH*4096 u32
constexpr size_t OFF_H2    = OFF_H1    + (size_t)2*BATCH*4096*4;       // 10*BATCH*4096 u32
constexpr size_t OFF_H3    = OFF_H2    + (size_t)10*BATCH*4096*4;      // 10*BATCH*256 u32
constexpr size_t OFF_ST1   = OFF_H3    + (size_t)10*BATCH*256*4;       // BATCH*16 int2
constexpr size_t OFF_ST2   = OFF_ST1   + (size_t)BATCH*16*8;
constexpr size_t OFF_OSTAB = OFF_ST2   + (size_t)BATCH*16*8;           // BATCH*16 f32
constexpr size_t OFF_OSTS  = OFF_OSTAB + (size_t)BATCH*16*4;
constexpr size_t OFF_SCAL  = OFF_OSTS  + (size_t)BATCH*16*4;           // BATCH*8 f32
constexpr size_t OFF_SPART = OFF_SCAL  + (size_t)BATCH*8*4;            // BATCH*64 f32
constexpr size_t OFF_PL1   = OFF_SPART + (size_t)BATCH*64*4;           // 4096 f32
constexpr size_t OFF_PG    = OFF_PL1   + 4096*4;                       // 1024 f32
constexpr size_t OFF_PSA   = OFF_PG    + 1024*4;
constexpr size_t OFF_PSB   = OFF_PSA   + 1024*4;
constexpr size_t OFF_P4    = OFF_PSB   + 1024*4;                       // 1024*4 f32

constexpr size_t QHIST_BYTES = (size_t)(2*BATCH*4096 + 10*BATCH*4096 + 10*BATCH*256)*4;

// scalar slots per image (index b*8+slot)
#define S_THR_IR 0
#define S_THR_VIS 1
#define S_THR_SUP 2
#define S_Q97A 3
#define S_Q97B 4
#define S_Q90S 5
#define S_Q97S 6
#define S_SALSUM 7

#define QH_BLOCKS 32

struct QRanks { int rank[10]; int arr[10]; int nr; };
struct GaussArg { float g[11]; };

__device__ __forceinline__ unsigned keymap(float x){
  unsigned u = __float_as_uint(x);
  return (u & 0x80000000u) ? ~u : (u | 0x80000000u);
}
__device__ __forceinline__ float invkey(unsigned k){
  unsigned bits = (k & 0x80000000u) ? (k ^ 0x80000000u) : ~k;
  return __uint_as_float(bits);
}

// ---------- saliency pools (separable, truncated SAME windows) ----------
template<int MIN>
__global__ void pool_x_k(const float* __restrict__ src, float* __restrict__ dst, int r){
  int i = blockIdx.x*256 + threadIdx.x;
  if (i >= NPIX) return;
  int x = i & (WID-1); int rb = i - x;
  int lo = x - r; if (lo < 0) lo = 0;
  int hi = x + r; if (hi > WID-1) hi = WID-1;
  float v = MIN ? 3.4e38f : -3.4e38f;
  for (int xx = lo; xx <= hi; ++xx){
    float s = src[rb + xx];
    v = MIN ? fminf(v, s) : fmaxf(v, s);
  }
  dst[i] = v;
}

template<int MIN>
__global__ void pool_y_k(const float* __restrict__ src, float* __restrict__ dst, int r){
  int i = blockIdx.x*256 + threadIdx.x;
  if (i >= NPIX) return;
  int b = i >> 18; int rem = i & (PIX-1);
  int y = rem >> 9; int x = rem & (WID-1);
  int lo = y - r; if (lo < 0) lo = 0;
  int hi = y + r; if (hi > HGT-1) hi = HGT-1;
  const float* sp = src + ((size_t)b << 18) + x;
  float v = MIN ? 3.4e38f : -3.4e38f;
  for (int yy = lo; yy <= hi; ++yy){
    float s = sp[yy << 9];
    v = MIN ? fminf(v, s) : fmaxf(v, s);
  }
  dst[i] = v;
}

// dilate-y fused with sal update: sal = max(sal, A - dilY(src))
__global__ void dilate_y_fuse_k(const float* __restrict__ src, const float* __restrict__ A,
                                float* __restrict__ sal, int r, int first){
  int i = blockIdx.x*256 + threadIdx.x;
  if (i >= NPIX) return;
  int b = i >> 18; int rem = i & (PIX-1);
  int y = rem >> 9; int x = rem & (WID-1);
  int lo = y - r; if (lo < 0) lo = 0;
  int hi = y + r; if (hi > HGT-1) hi = HGT-1;
  const float* sp = src + ((size_t)b << 18) + x;
  float v = -3.4e38f;
  for (int yy = lo; yy <= hi; ++yy) v = fmaxf(v, sp[yy << 9]);
  float s = A[i] - v;
  sal[i] = first ? s : fmaxf(sal[i], s);
}

// parallel per-image sum: 64 blocks/image -> partials -> wave combine
__global__ void salpart_k(const float* __restrict__ sal, float* __restrict__ part){
  __shared__ float red[256];
  int b = blockIdx.y;
  const float* sp = sal + (size_t)b*PIX;
  float s = 0.f;
  for (int i = blockIdx.x*256 + threadIdx.x; i < PIX; i += 64*256) s += sp[i];
  int t = threadIdx.x;
  red[t] = s; __syncthreads();
  for (int o = 128; o > 0; o >>= 1){ if (t < o) red[t] += red[t+o]; __syncthreads(); }
  if (t == 0) part[b*64 + blockIdx.x] = red[0];
}

__global__ void salfin_k(const float* __restrict__ part, float* __restrict__ scal){
  int t = threadIdx.x;          // 256 threads: 4 waves, one per image
  int b = t >> 6, lane = t & 63;
  float v = part[b*64 + lane];
  for (int o = 32; o > 0; o >>= 1) v += __shfl_down(v, o);
  if (lane == 0) scal[b*8 + S_SALSUM] = v;
}

__global__ void sal_norm_k(float* __restrict__ sal, const float* __restrict__ scal){
  int i = blockIdx.x*256 + threadIdx.x;
  if (i >= NPIX) return;
  int b = i >> 18;
  float mean = scal[b*8 + S_SALSUM] * (1.0f/(float)PIX);
  sal[i] = sal[i] / (mean + 1e-6f);
}

// ---------- exact quantile: three-level (12/12/8-bit) LDS-privatized select ----------
__global__ __launch_bounds__(256) void qh1_k(const float* __restrict__ X0, const float* __restrict__ X1,
                                             unsigned* __restrict__ h1){
  __shared__ unsigned hist[4096];
  int b = blockIdx.y, z = blockIdx.z;
  const float* p = (z ? X1 : X0) + (size_t)b*PIX;
  for (int i = threadIdx.x; i < 4096; i += 256) hist[i] = 0;
  __syncthreads();
  for (int i = blockIdx.x*256 + threadIdx.x; i < PIX; i += QH_BLOCKS*256){
    unsigned k = keymap(p[i]);
    atomicAdd(&hist[k >> 20], 1u);
  }
  __syncthreads();
  unsigned* g = h1 + ((size_t)(z*BATCH + b))*4096;
  for (int i = threadIdx.x; i < 4096; i += 256){
    unsigned c = hist[i];
    if (c) atomicAdd(&g[i], c);
  }
}

__global__ __launch_bounds__(1024) void qs1_k(const unsigned* __restrict__ h1, QRanks ra,
                                              int2* __restrict__ st1){
  __shared__ unsigned csum[1024];
  int zb = blockIdx.x; int z = zb / BATCH, b = zb % BATCH;
  const unsigned* h = h1 + (size_t)zb*4096;
  int t = threadIdx.x, base = t*4;
  unsigned c4[4]; unsigned own = 0;
  for (int j = 0; j < 4; ++j){ c4[j] = h[base+j]; own += c4[j]; }
  csum[t] = own; __syncthreads();
  for (int o = 1; o < 1024; o <<= 1){
    unsigned v = (t >= o) ? csum[t-o] : 0u;
    __syncthreads();
    csum[t] += v;
    __syncthreads();
  }
  unsigned incl = csum[t], excl = incl - own;
  for (int r = 0; r < ra.nr; ++r){
    if (ra.arr[r] != z) continue;
    unsigned rank = (unsigned)ra.rank[r];
    if (rank >= excl && rank < incl){
      unsigned rem = rank - excl;
      for (int j = 0; j < 4; ++j){
        if (rem < c4[j]){ st1[b*16 + r] = make_int2(base + j, (int)rem); break; }
        rem -= c4[j];
      }
    }
  }
}

__global__ __launch_bounds__(256) void qh2_k(const float* __restrict__ X0, const float* __restrict__ X1,
                                             const int2* __restrict__ st1, QRanks ra,
                                             unsigned* __restrict__ h2){
  __shared__ unsigned hist[4096];
  int b = blockIdx.y, r = blockIdx.z;
  int z = ra.arr[r];
  unsigned bin1 = (unsigned)st1[b*16 + r].x;
  const float* p = (z ? X1 : X0) + (size_t)b*PIX;
  for (int i = threadIdx.x; i < 4096; i += 256) hist[i] = 0;
  __syncthreads();
  for (int i = blockIdx.x*256 + threadIdx.x; i < PIX; i += QH_BLOCKS*256){
    unsigned k = keymap(p[i]);
    if ((k >> 20) == bin1) atomicAdd(&hist[(k >> 8) & 0xFFFu], 1u);
  }
  __syncthreads();
  unsigned* g = h2 + ((size_t)(r*BATCH + b))*4096;
  for (int i = threadIdx.x; i < 4096; i += 256){
    unsigned c = hist[i];
    if (c) atomicAdd(&g[i], c);
  }
}

__global__ __launch_bounds__(1024) void qs2_k(const unsigned* __restrict__ h2,
                                              const int2* __restrict__ st1, QRanks ra,
                                              int2* __restrict__ st2){
  __shared__ unsigned csum[1024];
  int rb = blockIdx.x; int r = rb / BATCH, b = rb % BATCH;
  const unsigned* h = h2 + (size_t)rb*4096;
  int t = threadIdx.x, base = t*4;
  unsigned c4[4]; unsigned own = 0;
  for (int j = 0; j < 4; ++j){ c4[j] = h[base+j]; own += c4[j]; }
  csum[t] = own; __syncthreads();
  for (int o = 1; o < 1024; o <<= 1){
    unsigned v = (t >= o) ? csum[t-o] : 0u;
    __syncthreads();
    csum[t] += v;
    __syncthreads();
  }
  unsigned rank = (unsigned)st1[b*16 + r].y;
  unsigned incl = csum[t], excl = incl - own;
  if (rank >= excl && rank < incl){
    unsigned rem = rank - excl;
    for (int j = 0; j < 4; ++j){
      if (rem < c4[j]){ st2[b*16 + r] = make_int2(base + j, (int)rem); break; }
      rem -= c4[j];
    }
  }
}

__global__ __launch_bounds__(256) void qh3_k(const float* __restrict__ X0, const float* __restrict__ X1,
                                             const int2* __restrict__ st1, const int2* __restrict__ st2,
                                             QRanks ra, unsigned* __restrict__ h3){
  __shared__ unsigned hist[256];
  int b = blockIdx.y, r = blockIdx.z;
  int z = ra.arr[r];
  unsigned top24 = ((unsigned)st1[b*16 + r].x << 12) | (unsigned)st2[b*16 + r].x;
  const float* p = (z ? X1 : X0) + (size_t)b*PIX;
  if (threadIdx.x < 256) hist[threadIdx.x] = 0;
  __syncthreads();
  for (int i = blockIdx.x*256 + threadIdx.x; i < PIX; i += QH_BLOCKS*256){
    unsigned k = keymap(p[i]);
    if ((k >> 8) == top24) atomicAdd(&hist[k & 0xFFu], 1u);
  }
  __syncthreads();
  unsigned* g = h3 + ((size_t)(r*BATCH + b))*256;
  unsigned c = hist[threadIdx.x];
  if (c) atomicAdd(&g[threadIdx.x], c);
}

__global__ __launch_bounds__(256) void qs3_k(const unsigned* __restrict__ h3,
                                             const int2* __restrict__ st1, const int2* __restrict__ st2,
                                             float* __restrict__ ostat){
  __shared__ unsigned csum[256];
  int rb = blockIdx.x; int r = rb / BATCH, b = rb % BATCH;
  const unsigned* h = h3 + (size_t)rb*256;
  int t = threadIdx.x;
  unsigned own = h[t];
  csum[t] = own; __syncthreads();
  for (int o = 1; o < 256; o <<= 1){
    unsigned v = (t >= o) ? csum[t-o] : 0u;
    __syncthreads();
    csum[t] += v;
    __syncthreads();
  }
  unsigned rank = (unsigned)st2[b*16 + r].y;
  unsigned incl = csum[t], excl = incl - own;
  if (rank >= excl && rank < incl){
    unsigned key = (((unsigned)st1[b*16 + r].x) << 20) | (((unsigned)st2[b*16 + r].x) << 8) | (unsigned)t;
    ostat[b*16 + r] = invkey(key);
  }
}

__global__ void finqAB_k(const float* __restrict__ ostat, float* __restrict__ scal,
                         float fA70, float fA97, float fB40, float fB85, float fB97){
  int b = threadIdx.x;
  if (b >= BATCH) return;
  const float* o = ostat + b*16;
  float q70  = o[0] + fA70*(o[1]-o[0]);
  float q97a = o[2] + fA97*(o[3]-o[2]);
  float q40  = o[4] + fB40*(o[5]-o[4]);
  float q85  = o[6] + fB85*(o[7]-o[6]);
  float q97b = o[8] + fB97*(o[9]-o[8]);
  scal[b*8 + S_THR_IR]  = fminf(fmaxf(q70, 0.45f), 0.85f);
  scal[b*8 + S_Q97A]    = q97a;
  scal[b*8 + S_THR_VIS] = fminf(fmaxf(q40, 0.3f),  0.7f);
  scal[b*8 + S_THR_SUP] = fminf(fmaxf(q85, 0.75f), 0.98f);
  scal[b*8 + S_Q97B]    = q97b;
}

__global__ void finqS_k(const float* __restrict__ ostat, float* __restrict__ scal,
                        float f90, float f97){
  int b = threadIdx.x;
  if (b >= BATCH) return;
  const float* o = ostat + b*16;
  scal[b*8 + S_Q90S] = o[0] + f90*(o[1]-o[0]);
  scal[b*8 + S_Q97S] = o[2] + f97*(o[3]-o[2]);
}

// ---------- masks ----------
__global__ void mlight_k(const float* __restrict__ A, const float* __restrict__ Bv,
                         const float* __restrict__ sal, const float* __restrict__ scal,
                         unsigned char* __restrict__ ml){
  int i = blockIdx.x*256 + threadIdx.x;
  if (i >= NPIX) return;
  int b = i >> 18;
  float q97s = scal[b*8 + S_Q97S], q97a = scal[b*8 + S_Q97A], q97b = scal[b*8 + S_Q97B];
  ml[i] = (sal[i] > q97s && A[i] > q97a && Bv[i] > q97b) ? 1 : 0;
}

// compact set pixels of M_light into per-image point lists
__global__ void compact_k(const unsigned char* __restrict__ ml, int* __restrict__ cnt,
                          int* __restrict__ pts){
  int i = blockIdx.x*256 + threadIdx.x;
  if (i >= NPIX || !ml[i]) return;
  int b = i >> 18;
  int idx = atomicAdd(&cnt[b], 1);
  pts[((size_t)b << 18) + idx] = i & (PIX-1);
}

// paint disk-50 around each point; one thread per dy row, u32-vectorized span
__global__ __launch_bounds__(128) void paint_k(const int* __restrict__ cnt, const int* __restrict__ pts,
                                               unsigned char* __restrict__ decay){
  int b = blockIdx.y;
  int n = cnt[b];
  for (int p = blockIdx.x; p < n; p += gridDim.x){
    int rem = pts[((size_t)b << 18) + p];
    int y = rem >> 9, x = rem & (WID-1);
    int t = threadIdx.x;
    if (t < 101){
      int dy = t - 50;
      int yy = y + dy;
      if (yy >= 0 && yy < HGT){
        int d2 = 2500 - dy*dy;
        int wd = (int)sqrtf((float)d2);
        while ((wd+1)*(wd+1) <= d2) ++wd;
        while (wd*wd > d2) --wd;
        int xl = x - wd; if (xl < 0) xl = 0;
        int xr = x + wd; if (xr > WID-1) xr = WID-1;
        unsigned char* row = decay + ((size_t)b << 18) + (yy << 9);
        int xx = xl;
        while (xx <= xr && (xx & 3)) row[xx++] = 1;
        for (; xx + 3 <= xr; xx += 4) *(unsigned*)(row + xx) = 0x01010101u;
        for (; xx <= xr; ++xx) row[xx] = 1;
      }
    }
  }
}

__global__ void bright_rowmax_k(const float* __restrict__ A, const float* __restrict__ scal,
                                float* __restrict__ t1){
  int i = blockIdx.x*256 + threadIdx.x;
  if (i >= NPIX) return;
  int b = i >> 18;
  float thr = scal[b*8 + S_Q97A];
  int x = i & (WID-1); int rb = i - x;
  int lo = x-7; if (lo < 0) lo = 0;
  int hi = x+7; if (hi > WID-1) hi = WID-1;
  float m = 0.f;
  for (int xx = lo; xx <= hi; ++xx) m = fmaxf(m, A[rb+xx] > thr ? 1.f : 0.f);
  t1[i] = m;
}

__global__ void halo_k(const float* __restrict__ t1, const float* __restrict__ A,
                       const float* __restrict__ scal, unsigned char* __restrict__ halo){
  int i = blockIdx.x*256 + threadIdx.x;
  if (i >= NPIX) return;
  int b = i >> 18; int rem = i & (PIX-1);
  int y = rem >> 9, x = rem & (WID-1);
  int lo = y-7; if (lo < 0) lo = 0;
  int hi = y+7; if (hi > HGT-1) hi = HGT-1;
  const float* sp = t1 + ((size_t)b << 18) + x;
  float d = 0.f;
  for (int yy = lo; yy <= hi; ++yy) d = fmaxf(d, sp[yy << 9]);
  float thr = scal[b*8 + S_Q97A];
  halo[i] = (d > 0.5f && !(A[i] > thr)) ? 1 : 0;
}

// ---------- loss_l1 ----------
__global__ void l1_k(const float* __restrict__ A, const float* __restrict__ Bv,
                     const float* __restrict__ F, const float* __restrict__ sal,
                     const float* __restrict__ scal, float* __restrict__ part){
  __shared__ float red[256];
  int i = blockIdx.x*256 + threadIdx.x;
  float s = 0.f;
  if (i < NPIX){
    int b = i >> 18;
    float a = A[i], v = Bv[i], f = F[i];
    float imx = fmaxf(a, v), imn = fminf(a, v);
    float thr_ir = scal[b*8 + S_THR_IR], thr_vis = scal[b*8 + S_THR_VIS];
    float thr_sup = scal[b*8 + S_THR_SUP], q90 = scal[b*8 + S_Q90S];
    float M = 1.f/(1.f + expf(-20.f*(sal[i] - q90)));
    bool irb = a > thr_ir, visb = v > thr_vis, viss = v > thr_sup;
    float salient = visb ? imn : imx;
    if (viss && irb) salient = imx;
    float target = M*salient + (1.f - M)*imx;
    s = fabsf(f - target);
  }
  int t = threadIdx.x;
  red[t] = s; __syncthreads();
  for (int o = 128; o > 0; o >>= 1){ if (t < o) red[t] += red[t+o]; __syncthreads(); }
  if (t == 0) part[blockIdx.x] = red[0];
}

// ---------- loss_grad (sobel) ----------
__device__ __forceinline__ float sobel_at(const float t[34][34], int ly, int lx){
  float gx = (t[ly-1][lx+1] - t[ly-1][lx-1]) + 2.f*(t[ly][lx+1] - t[ly][lx-1])
           + (t[ly+1][lx+1] - t[ly+1][lx-1]);
  float gy = (t[ly-1][lx-1] + 2.f*t[ly-1][lx] + t[ly-1][lx+1])
           - (t[ly+1][lx-1] + 2.f*t[ly+1][lx] + t[ly+1][lx+1]);
  return fabsf(gx) + fabsf(gy);
}

__global__ __launch_bounds__(1024) void grad_k(const float* __restrict__ A, const float* __restrict__ Bv,
                                               const float* __restrict__ F, float* __restrict__ part){
  __shared__ float ta[34][34], tb[34][34], tf[34][34];
  __shared__ float red[1024];
  int b = blockIdx.z;
  int y0 = blockIdx.y*32, x0 = blockIdx.x*32;
  int tid = threadIdx.y*32 + threadIdx.x;
  size_t ib = (size_t)b*PIX;
  for (int idx = tid; idx < 34*34; idx += 1024){
    int ly = idx/34, lx = idx%34;
    int gy = y0 + ly - 1, gx = x0 + lx - 1;
    float a = 0.f, v = 0.f, f = 0.f;
    if (gy >= 0 && gy < HGT && gx >= 0 && gx < WID){
      size_t g = ib + (size_t)gy*WID + gx;
      a = A[g]; v = Bv[g]; f = F[g];
    }
    ta[ly][lx] = a; tb[ly][lx] = v; tf[ly][lx] = f;
  }
  __syncthreads();
  int ly = threadIdx.y + 1, lx = threadIdx.x + 1;
  float ga = sobel_at(ta, ly, lx), gb = sobel_at(tb, ly, lx), gf = sobel_at(tf, ly, lx);
  float val = fabsf(gf - fmaxf(ga, gb));
  red[tid] = val; __syncthreads();
  for (int o = 512; o > 0; o >>= 1){ if (tid < o) red[tid] += red[tid+o]; __syncthreads(); }
  if (tid == 0){
    int blk = (blockIdx.z*gridDim.y + blockIdx.y)*gridDim.x + blockIdx.x;
    part[blk] = red[0];
  }
}

// ---------- SSIM (separable gaussian in LDS) ----------
__global__ __launch_bounds__(1024) void ssim_k(const float* __restrict__ X, const float* __restrict__ F,
                                               float* __restrict__ part, GaussArg gw){
  __shared__ float tx[42][42], tff[42][42];
  __shared__ float hx[42][32], hf[42][32], hxx[42][32], hff[42][32], hxf[42][32];
  __shared__ float red[1024];
  int b = blockIdx.z;
  int y0 = blockIdx.y*32, x0 = blockIdx.x*32;
  int tid = threadIdx.y*32 + threadIdx.x;
  size_t ib = (size_t)b*PIX;
  for (int idx = tid; idx < 42*42; idx += 1024){
    int ly = idx/42, lx = idx%42;
    int gy = y0 + ly - 5, gx = x0 + lx - 5;
    float xv = 0.f, fv = 0.f;
    if (gy >= 0 && gy < HGT && gx >= 0 && gx < WID){
      size_t g = ib + (size_t)gy*WID + gx;
      xv = X[g]; fv = F[g];
    }
    tx[ly][lx] = xv; tff[ly][lx] = fv;
  }
  __syncthreads();
  for (int idx = tid; idx < 42*32; idx += 1024){
    int row = idx/32, col = idx%32;
    float sx=0.f, sf=0.f, sxx=0.f, sff=0.f, sxf=0.f;
    for (int j = 0; j < 11; ++j){
      float g = gw.g[j];
      float xv = tx[row][col+j], fv = tff[row][col+j];
      sx += g*xv; sf += g*fv; sxx += g*xv*xv; sff += g*fv*fv; sxf += g*xv*fv;
    }
    hx[row][col]=sx; hf[row][col]=sf; hxx[row][col]=sxx; hff[row][col]=sff; hxf[row][col]=sxf;
  }
  __syncthreads();
  int ly = threadIdx.y, lx = threadIdx.x;
  float mu1=0.f, mu2=0.f, cxx=0.f, cff=0.f, cxf=0.f;
  for (int j = 0; j < 11; ++j){
    float g = gw.g[j];
    mu1 += g*hx[ly+j][lx]; mu2 += g*hf[ly+j][lx];
    cxx += g*hxx[ly+j][lx]; cff += g*hff[ly+j][lx]; cxf += g*hxf[ly+j][lx];
  }
  float m11 = mu1*mu1, m22 = mu2*mu2, m12 = mu1*mu2;
  float s1 = cxx - m11, s2 = cff - m22, s12 = cxf - m12;
  const float C1 = 1e-4f, C2 = 9e-4f;
  float m = ((2.f*m12 + C1)*(2.f*s12 + C2)) / ((m11 + m22 + C1)*(s1 + s2 + C2));
  red[tid] = m; __syncthreads();
  for (int o = 512; o > 0; o >>= 1){ if (tid < o) red[tid] += red[tid+o]; __syncthreads(); }
  if (tid == 0){
    int blk = (blockIdx.z*gridDim.y + blockIdx.y)*gridDim.x + blockIdx.x;
    part[blk] = red[0];
  }
}

// ---------- box blur 9 + halo/bloom sums ----------
__global__ __launch_bounds__(1024) void hb_k(const float* __restrict__ A, const float* __restrict__ Bv,
                                             const float* __restrict__ F, const float* __restrict__ sal,
                                             const float* __restrict__ scal,
                                             const unsigned char* __restrict__ ml,
                                             const unsigned char* __restrict__ halo,
                                             const unsigned char* __restrict__ decay,
                                             float* __restrict__ p4){
  __shared__ float ti[40][40], tv[40][40], tf[40][40];
  __shared__ float hi_[40][32], hv_[40][32], hf_[40][32];
  __shared__ float red[1024];
  int b = blockIdx.z;
  int y0 = blockIdx.y*32, x0 = blockIdx.x*32;
  int tid = threadIdx.y*32 + threadIdx.x;
  size_t ib = (size_t)b*PIX;
  for (int idx = tid; idx < 40*40; idx += 1024){
    int ly = idx/40, lx = idx%40;
    int gy = y0 + ly - 4, gx = x0 + lx - 4;
    float a = 0.f, v = 0.f, f = 0.f;
    if (gy >= 0 && gy < HGT && gx >= 0 && gx < WID){
      size_t g = ib + (size_t)gy*WID + gx;
      a = A[g]; v = Bv[g]; f = F[g];
    }
    ti[ly][lx] = a; tv[ly][lx] = v; tf[ly][lx] = f;
  }
  __syncthreads();
  for (int idx = tid; idx < 40*32; idx += 1024){
    int row = idx/32, col = idx%32;
    float si=0.f, sv=0.f, sf=0.f;
    for (int j = 0; j < 9; ++j){ si += ti[row][col+j]; sv += tv[row][col+j]; sf += tf[row][col+j]; }
    hi_[row][col]=si; hv_[row][col]=sv; hf_[row][col]=sf;
  }
  __syncthreads();
  int ly = threadIdx.y, lx = threadIdx.x;
  float si=0.f, sv=0.f, sf=0.f;
  for (int j = 0; j < 9; ++j){ si += hi_[ly+j][lx]; sv += hv_[ly+j][lx]; sf += hf_[ly+j][lx]; }
  const float inv81 = 1.f/81.f;
  float ib_ = si*inv81, vb_ = sv*inv81;
  float fb_ = fminf(fmaxf(sf*inv81, 0.f), 1.f);
  int gy = y0 + ly, gx = x0 + lx;
  size_t g = ib + (size_t)gy*WID + gx;
  float q90 = scal[b*8 + S_Q90S];
  float M = 1.f/(1.f + expf(-20.f*(sal[g] - q90)));
  float mh = (halo[g] && !ml[g] && decay[g]) ? 1.f : 0.f;
  float v1 = mh*fmaxf(fb_ - ib_, 0.f);
  float v3 = M*fmaxf(fb_ - vb_, 0.f);

  float vals[4] = {v1, mh, v3, M};
  float sums[4];
  for (int q = 0; q < 4; ++q){
    red[tid] = vals[q]; __syncthreads();
    for (int o = 512; o > 0; o >>= 1){ if (tid < o) red[tid] += red[tid+o]; __syncthreads(); }
    sums[q] = red[0]; __syncthreads();
  }
  if (tid == 0){
    int blk = (blockIdx.z*gridDim.y + blockIdx.y)*gridDim.x + blockIdx.x;
    p4[blk*4+0]=sums[0]; p4[blk*4+1]=sums[1]; p4[blk*4+2]=sums[2]; p4[blk*4+3]=sums[3];
  }
}

// ---------- final reduction ----------
__device__ float blk_sum_1024(float v, float* red){
  int t = threadIdx.x;
  red[t] = v; __syncthreads();
  for (int o = 512; o > 0; o >>= 1){ if (t < o) red[t] += red[t+o]; __syncthreads(); }
  float s = red[0]; __syncthreads();
  return s;
}

__global__ __launch_bounds__(1024) void final_k(const float* __restrict__ pl1, const float* __restrict__ pg,
                                                const float* __restrict__ psa, const float* __restrict__ psb,
                                                const float* __restrict__ p4, float* __restrict__ out){
  __shared__ float red[1024];
  int t = threadIdx.x;
  float v;
  v = 0.f; for (int i = t; i < 4096; i += 1024) v += pl1[i];
  float sumL1 = blk_sum_1024(v, red);
  v = 0.f; for (int i = t; i < 1024; i += 1024) v += pg[i];
  float sumG = blk_sum_1024(v, red);
  v = 0.f; for (int i = t; i < 1024; i += 1024) v += psa[i];
  float sA = blk_sum_1024(v, red);
  v = 0.f; for (int i = t; i < 1024; i += 1024) v += psb[i];
  float sB = blk_sum_1024(v, red);
  float s4[4];
  for (int q = 0; q < 4; ++q){
    v = 0.f; for (int i = t; i < 1024; i += 1024) v += p4[i*4+q];
    s4[q] = blk_sum_1024(v, red);
  }
  if (t == 0){
    const float inv = 1.f/(float)NPIX;
    float loss_l1 = 15.f*sumL1*inv;
    float loss_grad = 14.f*sumG*inv;
    float loss_ssim = 20.f*(1.f - 0.5f*sA*inv - 0.5f*sB*inv);
    float lh = s4[0] / fmaxf(s4[1] + 1e-6f, 1.f);
    float lb = s4[2] / fmaxf(s4[3] + 1e-6f, 1.f);
    float whb = 0.3f*lh + 0.6f*lb;
    out[0] = loss_l1 + loss_grad + loss_ssim + whb;
    out[1] = loss_grad;
    out[2] = loss_l1;
    out[3] = loss_ssim;
    out[4] = whb;
  }
}

// ---------- host ----------
extern "C" void kernel_launch(void* const* d_in, const int* in_sizes, int n_in,
                              void* d_out, int out_size, void* d_ws, size_t ws_size,
                              hipStream_t stream) {
  const float* A  = (const float*)d_in[0];
  const float* Bv = (const float*)d_in[1];
  const float* F  = (const float*)d_in[2];
  float* out = (float*)d_out;
  char* w = (char*)d_ws;

  float* sal = (float*)(w + OFF_SAL);
  float* t1  = (float*)(w + OFF_T1);
  float* t2  = (float*)(w + OFF_T2);
  unsigned char* ml    = (unsigned char*)(w + OFF_ML);
  unsigned char* halo  = (unsigned char*)(w + OFF_HALO);
  unsigned char* decay = (unsigned char*)(w + OFF_DECAY);
  int* cnt = (int*)(w + OFF_CNT);
  int* pts = (int*)(w + OFF_PTS);
  unsigned* h1 = (unsigned*)(w + OFF_H1);
  unsigned* h2 = (unsigned*)(w + OFF_H2);
  unsigned* h3 = (unsigned*)(w + OFF_H3);
  int2* st1 = (int2*)(w + OFF_ST1);
  int2* st2 = (int2*)(w + OFF_ST2);
  float* ostAB = (float*)(w + OFF_OSTAB);
  float* ostS  = (float*)(w + OFF_OSTS);
  float* scal  = (float*)(w + OFF_SCAL);
  float* spart = (float*)(w + OFF_SPART);
  float* pl1 = (float*)(w + OFF_PL1);
  float* pg  = (float*)(w + OFF_PG);
  float* psa = (float*)(w + OFF_PSA);
  float* psb = (float*)(w + OFF_PSB);
  float* p4  = (float*)(w + OFF_P4);

  dim3 b256(256), g4096(NPIX/256);
  dim3 gt(WID/32, HGT/32, BATCH), bt(32, 32);

  // ---- rank positions (exact order statistics k, k+1 + fraction) ----
  auto mkrank = [](double q, int* k0, double* fr){
    double pos = q*(double)(PIX-1);
    double fl = floor(pos);
    *k0 = (int)fl; *fr = pos - fl;
  };
  int kA70, kA97, kB40, kB85, kB97, kS90, kS97;
  double fA70, fA97, fB40, fB85, fB97, fS90, fS97;
  mkrank(0.70, &kA70, &fA70); mkrank(0.97, &kA97, &fA97);
  mkrank(0.40, &kB40, &fB40); mkrank(0.85, &kB85, &fB85); mkrank(0.97, &kB97, &fB97);
  mkrank(0.90, &kS90, &fS90); mkrank(0.97, &kS97, &fS97);

  // ---- A+B quantiles (independent of saliency; issue first) ----
  {
    QRanks ra{};
    int rr[10]  = {kA70, kA70+1, kA97, kA97+1, kB40, kB40+1, kB85, kB85+1, kB97, kB97+1};
    int aa[10]  = {0,0,0,0, 1,1,1,1,1,1};
    for (int i = 0; i < 10; ++i){ ra.rank[i]=rr[i]; ra.arr[i]=aa[i]; }
    ra.nr = 10;
    hipMemsetAsync(w + OFF_H1, 0, QHIST_BYTES, stream);
    qh1_k<<<dim3(QH_BLOCKS, BATCH, 2), b256, 0, stream>>>(A, Bv, h1);
    qs1_k<<<2*BATCH, 1024, 0, stream>>>(h1, ra, st1);
    qh2_k<<<dim3(QH_BLOCKS, BATCH, 10), b256, 0, stream>>>(A, Bv, st1, ra, h2);
    qs2_k<<<10*BATCH, 1024, 0, stream>>>(h2, st1, ra, st2);
    qh3_k<<<dim3(QH_BLOCKS, BATCH, 10), b256, 0, stream>>>(A, Bv, st1, st2, ra, h3);
    qs3_k<<<10*BATCH, 256, 0, stream>>>(h3, st1, st2, ostAB);
    finqAB_k<<<1, BATCH, 0, stream>>>(ostAB, scal, (float)fA70, (float)fA97,
                                      (float)fB40, (float)fB85, (float)fB97);
  }

  // ---- saliency: sal = max_k (A - opening(A,k)), then normalize by per-image mean ----
  const int ks[3] = {9, 15, 31};
  for (int ki = 0; ki < 3; ++ki){
    int r = ks[ki]/2;
    pool_x_k<1><<<g4096, b256, 0, stream>>>(A,  t1, r);
    pool_y_k<1><<<g4096, b256, 0, stream>>>(t1, t2, r);
    pool_x_k<0><<<g4096, b256, 0, stream>>>(t2, t1, r);
    dilate_y_fuse_k<<<g4096, b256, 0, stream>>>(t1, A, sal, r, ki == 0 ? 1 : 0);
  }
  salpart_k<<<dim3(64, BATCH), b256, 0, stream>>>(sal, spart);
  salfin_k<<<1, 256, 0, stream>>>(spart, scal);
  sal_norm_k<<<g4096, b256, 0, stream>>>(sal, scal);

  // ---- sal quantiles ----
  {
    QRanks ra{};
    int rr[4] = {kS90, kS90+1, kS97, kS97+1};
    for (int i = 0; i < 4; ++i){ ra.rank[i]=rr[i]; ra.arr[i]=0; }
    ra.nr = 4;
    hipMemsetAsync(w + OFF_H1, 0, QHIST_BYTES, stream);
    qh1_k<<<dim3(QH_BLOCKS, BATCH, 1), b256, 0, stream>>>(sal, sal, h1);
    qs1_k<<<1*BATCH, 1024, 0, stream>>>(h1, ra, st1);
    qh2_k<<<dim3(QH_BLOCKS, BATCH, 4), b256, 0, stream>>>(sal, sal, st1, ra, h2);
    qs2_k<<<4*BATCH, 1024, 0, stream>>>(h2, st1, ra, st2);
    qh3_k<<<dim3(QH_BLOCKS, BATCH, 4), b256, 0, stream>>>(sal, sal, st1, st2, ra, h3);
    qs3_k<<<4*BATCH, 256, 0, stream>>>(h3, st1, st2, ostS);
    finqS_k<<<1, BATCH, 0, stream>>>(ostS, scal, (float)fS90, (float)fS97);
  }

  // ---- masks: M_light, decay (disk-50 via compact+paint), halo ----
  mlight_k<<<g4096, b256, 0, stream>>>(A, Bv, sal, scal, ml);
  hipMemsetAsync(w + OFF_CNT, 0, 64, stream);
  hipMemsetAsync(w + OFF_DECAY, 0, (size_t)NPIX, stream);
  compact_k<<<g4096, b256, 0, stream>>>(ml, cnt, pts);
  paint_k<<<dim3(256, BATCH), 128, 0, stream>>>(cnt, pts, decay);
  bright_rowmax_k<<<g4096, b256, 0, stream>>>(A, scal, t1);
  halo_k<<<g4096, b256, 0, stream>>>(t1, A, scal, halo);

  // ---- losses ----
  l1_k<<<g4096, b256, 0, stream>>>(A, Bv, F, sal, scal, pl1);
  grad_k<<<gt, bt, 0, stream>>>(A, Bv, F, pg);

  GaussArg ga{};
  {
    double g[11], s = 0.0;
    for (int i = 0; i < 11; ++i){ double d = (double)(i-5); g[i] = exp(-(d*d)/4.5); s += g[i]; }
    for (int i = 0; i < 11; ++i) ga.g[i] = (float)(g[i]/s);
  }
  ssim_k<<<gt, bt, 0, stream>>>(A,  F, psa, ga);
  ssim_k<<<gt, bt, 0, stream>>>(Bv, F, psb, ga);

  hb_k<<<gt, bt, 0, stream>>>(A, Bv, F, sal, scal, ml, halo, decay, p4);

  final_k<<<1, 1024, 0, stream>>>(pl1, pg, psa, psb, p4, out);
}

// Round 4
// 207.880 us; speedup vs baseline: 6.2445x; 1.7123x over previous
//
#include <hip/hip_runtime.h>
#include <cmath>

#define BATCH 4
#define HGT 512
#define WID 512
#define PIX (HGT*WID)        // 262144 = 2^18
#define NPIX (BATCH*PIX)     // 1048576

// ---------- ws layout (bytes) ----------
constexpr size_t OFF_SAL   = 0;                                       // NPIX f32 (raw saliency)
constexpr size_t OFF_ERO   = OFF_SAL  + (size_t)NPIX*4;               // NPIX f32 (eroded tmp)
constexpr size_t OFF_ML    = OFF_ERO  + (size_t)NPIX*4;               // NPIX u8
constexpr size_t OFF_HALO  = OFF_ML   + (size_t)NPIX;                 // NPIX u8
constexpr size_t OFF_DECAY = OFF_HALO + (size_t)NPIX;                 // NPIX u8
constexpr size_t OFF_CNT   = OFF_DECAY+ (size_t)NPIX;                 // BATCH i32 (+pad)
constexpr size_t OFF_PTS   = OFF_CNT  + 64;                           // NPIX i32
constexpr size_t OFF_H1    = OFF_PTS  + (size_t)NPIX*4;               // 3*B*4096 u32
constexpr size_t OFF_H2    = OFF_H1   + (size_t)3*BATCH*4096*4;       // 14*B*4096 u32
constexpr size_t OFF_H3    = OFF_H2   + (size_t)14*BATCH*4096*4;      // 14*B*256 u32
constexpr size_t OFF_ST1   = OFF_H3   + (size_t)14*BATCH*256*4;       // B*16 int2
constexpr size_t OFF_ST2   = OFF_ST1  + (size_t)BATCH*16*8;
constexpr size_t OFF_OST   = OFF_ST2  + (size_t)BATCH*16*8;           // B*16 f32
constexpr size_t OFF_SCAL  = OFF_OST  + (size_t)BATCH*16*4;           // B*16 f32
constexpr size_t OFF_SPART = OFF_SCAL + (size_t)BATCH*16*4;           // 1024 f32
constexpr size_t OFF_PG    = OFF_SPART+ 1024*4;                       // 1024 f32
constexpr size_t OFF_PSA   = OFF_PG   + 1024*4;
constexpr size_t OFF_PSB   = OFF_PSA  + 1024*4;
constexpr size_t OFF_P5    = OFF_PSB  + 1024*4;                       // 1024*5 f32

constexpr size_t QHIST_BYTES = (size_t)(3*BATCH*4096 + 14*BATCH*4096 + 14*BATCH*256)*4;

// scalar slots per image (index b*16+slot)
#define S_THR_IR 0
#define S_THR_VIS 1
#define S_THR_SUP 2
#define S_Q97A 3
#define S_Q97B 4
#define S_Q90S 5
#define S_Q97S 6
#define S_SALSUM 7
#define S_KM 8

#define QH_BLOCKS 32

struct QRanks { int rank[14]; int arr[14]; int nr; };
struct GaussArg { float g[11]; };
struct FracArg { float fA70, fA97, fB40, fB85, fB97, fS90, fS97; };

__device__ __forceinline__ unsigned keymap(float x){
  unsigned u = __float_as_uint(x);
  return (u & 0x80000000u) ? ~u : (u | 0x80000000u);
}
__device__ __forceinline__ float invkey(unsigned k){
  unsigned bits = (k & 0x80000000u) ? (k ^ 0x80000000u) : ~k;
  return __uint_as_float(bits);
}

// ---------- fused tiled erosion (minX+minY in LDS), truncated SAME window ----------
template<int R>
__global__ __launch_bounds__(1024) void erode_k(const float* __restrict__ A, float* __restrict__ ero){
  constexpr int TW = 32 + 2*R;
  __shared__ float tA[TW][TW];
  __shared__ float mX[TW][32];
  int b = blockIdx.z;
  int y0 = blockIdx.y*32, x0 = blockIdx.x*32;
  int tid = threadIdx.y*32 + threadIdx.x;
  const float* Ab = A + ((size_t)b << 18);
  for (int idx = tid; idx < TW*TW; idx += 1024){
    int ly = idx / TW, lx = idx % TW;
    int gy = y0 + ly - R, gx = x0 + lx - R;
    float v = 3.4e38f;
    if (gy >= 0 && gy < HGT && gx >= 0 && gx < WID) v = Ab[(gy << 9) + gx];
    tA[ly][lx] = v;
  }
  __syncthreads();
  for (int idx = tid; idx < TW*32; idx += 1024){
    int row = idx >> 5, c = idx & 31;
    float m = 3.4e38f;
    #pragma unroll
    for (int j = 0; j <= 2*R; ++j) m = fminf(m, tA[row][c+j]);
    mX[row][c] = m;
  }
  __syncthreads();
  int ly = threadIdx.y, lx = threadIdx.x;
  float m = 3.4e38f;
  #pragma unroll
  for (int j = 0; j <= 2*R; ++j) m = fminf(m, mX[ly+j][lx]);
  ero[((size_t)b << 18) + ((size_t)(y0+ly) << 9) + (x0+lx)] = m;
}

// ---------- fused tiled dilation + sal update (+ block partial sums on LAST) ----------
template<int R, int FIRST, int LAST>
__global__ __launch_bounds__(1024) void dilate_k(const float* __restrict__ ero, const float* __restrict__ A,
                                                 float* __restrict__ sal, float* __restrict__ spart){
  constexpr int TW = 32 + 2*R;
  __shared__ float tE[TW][TW];
  __shared__ float mX[TW][32];
  __shared__ float red[1024];
  int b = blockIdx.z;
  int y0 = blockIdx.y*32, x0 = blockIdx.x*32;
  int tid = threadIdx.y*32 + threadIdx.x;
  const float* Eb = ero + ((size_t)b << 18);
  for (int idx = tid; idx < TW*TW; idx += 1024){
    int ly = idx / TW, lx = idx % TW;
    int gy = y0 + ly - R, gx = x0 + lx - R;
    float v = -3.4e38f;
    if (gy >= 0 && gy < HGT && gx >= 0 && gx < WID) v = Eb[(gy << 9) + gx];
    tE[ly][lx] = v;
  }
  __syncthreads();
  for (int idx = tid; idx < TW*32; idx += 1024){
    int row = idx >> 5, c = idx & 31;
    float m = -3.4e38f;
    #pragma unroll
    for (int j = 0; j <= 2*R; ++j) m = fmaxf(m, tE[row][c+j]);
    mX[row][c] = m;
  }
  __syncthreads();
  int ly = threadIdx.y, lx = threadIdx.x;
  float m = -3.4e38f;
  #pragma unroll
  for (int j = 0; j <= 2*R; ++j) m = fmaxf(m, mX[ly+j][lx]);
  size_t g = ((size_t)b << 18) + ((size_t)(y0+ly) << 9) + (x0+lx);
  float s = A[g] - m;
  float sv = FIRST ? s : fmaxf(sal[g], s);
  sal[g] = sv;
  if (LAST){
    red[tid] = sv; __syncthreads();
    for (int o = 512; o > 0; o >>= 1){ if (tid < o) red[tid] += red[tid+o]; __syncthreads(); }
    if (tid == 0) spart[b*256 + blockIdx.y*16 + blockIdx.x] = red[0];
  }
}

__global__ void salfin_k(const float* __restrict__ part, float* __restrict__ scal){
  __shared__ float red[256];
  int b = blockIdx.x, t = threadIdx.x;
  red[t] = part[b*256 + t]; __syncthreads();
  for (int o = 128; o > 0; o >>= 1){ if (t < o) red[t] += red[t+o]; __syncthreads(); }
  if (t == 0) scal[b*16 + S_SALSUM] = red[0];
}

// ---------- exact quantile: three-level (12/12/8-bit) LDS-privatized select, 3 arrays ----------
__global__ __launch_bounds__(256) void qh1_k(const float* __restrict__ X0, const float* __restrict__ X1,
                                             const float* __restrict__ X2, unsigned* __restrict__ h1){
  __shared__ unsigned hist[4096];
  int b = blockIdx.y, z = blockIdx.z;
  const float* p = (z == 0 ? X0 : (z == 1 ? X1 : X2)) + (size_t)b*PIX;
  for (int i = threadIdx.x; i < 4096; i += 256) hist[i] = 0;
  __syncthreads();
  for (int i = blockIdx.x*256 + threadIdx.x; i < PIX; i += QH_BLOCKS*256){
    unsigned k = keymap(p[i]);
    atomicAdd(&hist[k >> 20], 1u);
  }
  __syncthreads();
  unsigned* g = h1 + ((size_t)(z*BATCH + b))*4096;
  for (int i = threadIdx.x; i < 4096; i += 256){
    unsigned c = hist[i];
    if (c) atomicAdd(&g[i], c);
  }
}

__global__ __launch_bounds__(1024) void qs1_k(const unsigned* __restrict__ h1, QRanks ra,
                                              int2* __restrict__ st1){
  __shared__ unsigned csum[1024];
  int zb = blockIdx.x; int z = zb / BATCH, b = zb % BATCH;
  const unsigned* h = h1 + (size_t)zb*4096;
  int t = threadIdx.x, base = t*4;
  unsigned c4[4]; unsigned own = 0;
  for (int j = 0; j < 4; ++j){ c4[j] = h[base+j]; own += c4[j]; }
  csum[t] = own; __syncthreads();
  for (int o = 1; o < 1024; o <<= 1){
    unsigned v = (t >= o) ? csum[t-o] : 0u;
    __syncthreads();
    csum[t] += v;
    __syncthreads();
  }
  unsigned incl = csum[t], excl = incl - own;
  for (int r = 0; r < ra.nr; ++r){
    if (ra.arr[r] != z) continue;
    unsigned rank = (unsigned)ra.rank[r];
    if (rank >= excl && rank < incl){
      unsigned rem = rank - excl;
      for (int j = 0; j < 4; ++j){
        if (rem < c4[j]){ st1[b*16 + r] = make_int2(base + j, (int)rem); break; }
        rem -= c4[j];
      }
    }
  }
}

__global__ __launch_bounds__(256) void qh2_k(const float* __restrict__ X0, const float* __restrict__ X1,
                                             const float* __restrict__ X2,
                                             const int2* __restrict__ st1, QRanks ra,
                                             unsigned* __restrict__ h2){
  __shared__ unsigned hist[4096];
  int b = blockIdx.y, r = blockIdx.z;
  int z = ra.arr[r];
  unsigned bin1 = (unsigned)st1[b*16 + r].x;
  const float* p = (z == 0 ? X0 : (z == 1 ? X1 : X2)) + (size_t)b*PIX;
  for (int i = threadIdx.x; i < 4096; i += 256) hist[i] = 0;
  __syncthreads();
  for (int i = blockIdx.x*256 + threadIdx.x; i < PIX; i += QH_BLOCKS*256){
    unsigned k = keymap(p[i]);
    if ((k >> 20) == bin1) atomicAdd(&hist[(k >> 8) & 0xFFFu], 1u);
  }
  __syncthreads();
  unsigned* g = h2 + ((size_t)(r*BATCH + b))*4096;
  for (int i = threadIdx.x; i < 4096; i += 256){
    unsigned c = hist[i];
    if (c) atomicAdd(&g[i], c);
  }
}

__global__ __launch_bounds__(1024) void qs2_k(const unsigned* __restrict__ h2,
                                              const int2* __restrict__ st1, QRanks ra,
                                              int2* __restrict__ st2){
  __shared__ unsigned csum[1024];
  int rb = blockIdx.x; int r = rb / BATCH, b = rb % BATCH;
  const unsigned* h = h2 + (size_t)rb*4096;
  int t = threadIdx.x, base = t*4;
  unsigned c4[4]; unsigned own = 0;
  for (int j = 0; j < 4; ++j){ c4[j] = h[base+j]; own += c4[j]; }
  csum[t] = own; __syncthreads();
  for (int o = 1; o < 1024; o <<= 1){
    unsigned v = (t >= o) ? csum[t-o] : 0u;
    __syncthreads();
    csum[t] += v;
    __syncthreads();
  }
  unsigned rank = (unsigned)st1[b*16 + r].y;
  unsigned incl = csum[t], excl = incl - own;
  if (rank >= excl && rank < incl){
    unsigned rem = rank - excl;
    for (int j = 0; j < 4; ++j){
      if (rem < c4[j]){ st2[b*16 + r] = make_int2(base + j, (int)rem); break; }
      rem -= c4[j];
    }
  }
}

__global__ __launch_bounds__(256) void qh3_k(const float* __restrict__ X0, const float* __restrict__ X1,
                                             const float* __restrict__ X2,
                                             const int2* __restrict__ st1, const int2* __restrict__ st2,
                                             QRanks ra, unsigned* __restrict__ h3){
  __shared__ unsigned hist[256];
  int b = blockIdx.y, r = blockIdx.z;
  int z = ra.arr[r];
  unsigned top24 = ((unsigned)st1[b*16 + r].x << 12) | (unsigned)st2[b*16 + r].x;
  const float* p = (z == 0 ? X0 : (z == 1 ? X1 : X2)) + (size_t)b*PIX;
  hist[threadIdx.x] = 0;
  __syncthreads();
  for (int i = blockIdx.x*256 + threadIdx.x; i < PIX; i += QH_BLOCKS*256){
    unsigned k = keymap(p[i]);
    if ((k >> 8) == top24) atomicAdd(&hist[k & 0xFFu], 1u);
  }
  __syncthreads();
  unsigned* g = h3 + ((size_t)(r*BATCH + b))*256;
  unsigned c = hist[threadIdx.x];
  if (c) atomicAdd(&g[threadIdx.x], c);
}

__global__ __launch_bounds__(256) void qs3_k(const unsigned* __restrict__ h3,
                                             const int2* __restrict__ st1, const int2* __restrict__ st2,
                                             float* __restrict__ ostat){
  __shared__ unsigned csum[256];
  int rb = blockIdx.x; int r = rb / BATCH, b = rb % BATCH;
  const unsigned* h = h3 + (size_t)rb*256;
  int t = threadIdx.x;
  unsigned own = h[t];
  csum[t] = own; __syncthreads();
  for (int o = 1; o < 256; o <<= 1){
    unsigned v = (t >= o) ? csum[t-o] : 0u;
    __syncthreads();
    csum[t] += v;
    __syncthreads();
  }
  unsigned rank = (unsigned)st2[b*16 + r].y;
  unsigned incl = csum[t], excl = incl - own;
  if (rank >= excl && rank < incl){
    unsigned key = (((unsigned)st1[b*16 + r].x) << 20) | (((unsigned)st2[b*16 + r].x) << 8) | (unsigned)t;
    ostat[b*16 + r] = invkey(key);
  }
}

// all scalars: thresholds (clipped), raw sal quantiles, kM = 20/c
__global__ void finq_k(const float* __restrict__ ostat, float* __restrict__ scal, FracArg fr){
  int b = threadIdx.x;
  if (b >= BATCH) return;
  const float* o = ostat + b*16;
  float q70  = o[0]  + fr.fA70*(o[1]-o[0]);
  float q97a = o[2]  + fr.fA97*(o[3]-o[2]);
  float q40  = o[4]  + fr.fB40*(o[5]-o[4]);
  float q85  = o[6]  + fr.fB85*(o[7]-o[6]);
  float q97b = o[8]  + fr.fB97*(o[9]-o[8]);
  float q90s = o[10] + fr.fS90*(o[11]-o[10]);
  float q97s = o[12] + fr.fS97*(o[13]-o[12]);
  float c = scal[b*16 + S_SALSUM]*(1.0f/(float)PIX) + 1e-6f;
  scal[b*16 + S_THR_IR]  = fminf(fmaxf(q70, 0.45f), 0.85f);
  scal[b*16 + S_Q97A]    = q97a;
  scal[b*16 + S_THR_VIS] = fminf(fmaxf(q40, 0.3f),  0.7f);
  scal[b*16 + S_THR_SUP] = fminf(fmaxf(q85, 0.75f), 0.98f);
  scal[b*16 + S_Q97B]    = q97b;
  scal[b*16 + S_Q90S]    = q90s;       // raw-space
  scal[b*16 + S_Q97S]    = q97s;       // raw-space
  scal[b*16 + S_KM]      = 20.0f / c;  // sigmoid slope in raw space
}

// ---------- masks ----------
__global__ void mlight_compact_k(const float* __restrict__ A, const float* __restrict__ Bv,
                                 const float* __restrict__ sal, const float* __restrict__ scal,
                                 unsigned char* __restrict__ ml, int* __restrict__ cnt,
                                 int* __restrict__ pts){
  int i = blockIdx.x*256 + threadIdx.x;
  if (i >= NPIX) return;
  int b = i >> 18;
  bool m = (sal[i] > scal[b*16 + S_Q97S]) && (A[i] > scal[b*16 + S_Q97A]) && (Bv[i] > scal[b*16 + S_Q97B]);
  ml[i] = m ? 1 : 0;
  if (m){
    int idx = atomicAdd(&cnt[b], 1);
    pts[((size_t)b << 18) + idx] = i & (PIX-1);
  }
}

// paint disk-50 around each point; one thread per dy row, u32-vectorized span
__global__ __launch_bounds__(128) void paint_k(const int* __restrict__ cnt, const int* __restrict__ pts,
                                               unsigned char* __restrict__ decay){
  int b = blockIdx.y;
  int n = cnt[b];
  for (int p = blockIdx.x; p < n; p += gridDim.x){
    int rem = pts[((size_t)b << 18) + p];
    int y = rem >> 9, x = rem & (WID-1);
    int t = threadIdx.x;
    if (t < 101){
      int dy = t - 50;
      int yy = y + dy;
      if (yy >= 0 && yy < HGT){
        int d2 = 2500 - dy*dy;
        int wd = (int)sqrtf((float)d2);
        while ((wd+1)*(wd+1) <= d2) ++wd;
        while (wd*wd > d2) --wd;
        int xl = x - wd; if (xl < 0) xl = 0;
        int xr = x + wd; if (xr > WID-1) xr = WID-1;
        unsigned char* row = decay + ((size_t)b << 18) + (yy << 9);
        int xx = xl;
        while (xx <= xr && (xx & 3)) row[xx++] = 1;
        for (; xx + 3 <= xr; xx += 4) *(unsigned*)(row + xx) = 0x01010101u;
        for (; xx <= xr; ++xx) row[xx] = 1;
      }
    }
  }
}

// fused bright (A>q97A) -> 15x15 dilate -> halo mask, tiled in LDS
__global__ __launch_bounds__(1024) void brighthalo_k(const float* __restrict__ A,
                                                     const float* __restrict__ scal,
                                                     unsigned char* __restrict__ halo){
  constexpr int R = 7, TW = 32 + 2*R; // 46
  __shared__ float bt[TW][TW];
  __shared__ float dX[TW][32];
  int b = blockIdx.z;
  float thr = scal[b*16 + S_Q97A];
  int y0 = blockIdx.y*32, x0 = blockIdx.x*32;
  int tid = threadIdx.y*32 + threadIdx.x;
  const float* Ab = A + ((size_t)b << 18);
  for (int idx = tid; idx < TW*TW; idx += 1024){
    int ly = idx / TW, lx = idx % TW;
    int gy = y0 + ly - R, gx = x0 + lx - R;
    float v = 0.f;
    if (gy >= 0 && gy < HGT && gx >= 0 && gx < WID) v = (Ab[(gy << 9) + gx] > thr) ? 1.f : 0.f;
    bt[ly][lx] = v;
  }
  __syncthreads();
  for (int idx = tid; idx < TW*32; idx += 1024){
    int row = idx >> 5, c = idx & 31;
    float m = 0.f;
    #pragma unroll
    for (int j = 0; j <= 2*R; ++j) m = fmaxf(m, bt[row][c+j]);
    dX[row][c] = m;
  }
  __syncthreads();
  int ly = threadIdx.y, lx = threadIdx.x;
  float m = 0.f;
  #pragma unroll
  for (int j = 0; j <= 2*R; ++j) m = fmaxf(m, dX[ly+j][lx]);
  bool brightc = bt[ly+R][lx+R] > 0.5f;
  halo[((size_t)b << 18) + ((size_t)(y0+ly) << 9) + (x0+lx)] = (m > 0.5f && !brightc) ? 1 : 0;
}

// ---------- loss_grad (sobel) ----------
__device__ __forceinline__ float sobel_at(const float t[34][34], int ly, int lx){
  float gx = (t[ly-1][lx+1] - t[ly-1][lx-1]) + 2.f*(t[ly][lx+1] - t[ly][lx-1])
           + (t[ly+1][lx+1] - t[ly+1][lx-1]);
  float gy = (t[ly-1][lx-1] + 2.f*t[ly-1][lx] + t[ly-1][lx+1])
           - (t[ly+1][lx-1] + 2.f*t[ly+1][lx] + t[ly+1][lx+1]);
  return fabsf(gx) + fabsf(gy);
}

__global__ __launch_bounds__(1024) void grad_k(const float* __restrict__ A, const float* __restrict__ Bv,
                                               const float* __restrict__ F, float* __restrict__ part){
  __shared__ float ta[34][34], tb[34][34], tf[34][34];
  __shared__ float red[1024];
  int b = blockIdx.z;
  int y0 = blockIdx.y*32, x0 = blockIdx.x*32;
  int tid = threadIdx.y*32 + threadIdx.x;
  size_t ib = (size_t)b*PIX;
  for (int idx = tid; idx < 34*34; idx += 1024){
    int ly = idx/34, lx = idx%34;
    int gy = y0 + ly - 1, gx = x0 + lx - 1;
    float a = 0.f, v = 0.f, f = 0.f;
    if (gy >= 0 && gy < HGT && gx >= 0 && gx < WID){
      size_t g = ib + (size_t)gy*WID + gx;
      a = A[g]; v = Bv[g]; f = F[g];
    }
    ta[ly][lx] = a; tb[ly][lx] = v; tf[ly][lx] = f;
  }
  __syncthreads();
  int ly = threadIdx.y + 1, lx = threadIdx.x + 1;
  float ga = sobel_at(ta, ly, lx), gb = sobel_at(tb, ly, lx), gf = sobel_at(tf, ly, lx);
  float val = fabsf(gf - fmaxf(ga, gb));
  red[tid] = val; __syncthreads();
  for (int o = 512; o > 0; o >>= 1){ if (tid < o) red[tid] += red[tid+o]; __syncthreads(); }
  if (tid == 0){
    int blk = (blockIdx.z*gridDim.y + blockIdx.y)*gridDim.x + blockIdx.x;
    part[blk] = red[0];
  }
}

// ---------- SSIM both pairs in one kernel (LDS plane reuse) ----------
__global__ __launch_bounds__(1024) void ssim2_k(const float* __restrict__ A, const float* __restrict__ Bv,
                                                const float* __restrict__ F,
                                                float* __restrict__ psa, float* __restrict__ psb,
                                                GaussArg gw){
  __shared__ float ta[42][42], tb[42][42], tf[42][42];
  __shared__ float hx[42][32], hf[42][32], hxx[42][32], hff[42][32], hxf[42][32];
  __shared__ float red[1024];
  int b = blockIdx.z;
  int y0 = blockIdx.y*32, x0 = blockIdx.x*32;
  int tid = threadIdx.y*32 + threadIdx.x;
  size_t ib = (size_t)b*PIX;
  for (int idx = tid; idx < 42*42; idx += 1024){
    int ly = idx/42, lx = idx%42;
    int gy = y0 + ly - 5, gx = x0 + lx - 5;
    float av = 0.f, bv = 0.f, fv = 0.f;
    if (gy >= 0 && gy < HGT && gx >= 0 && gx < WID){
      size_t g = ib + (size_t)gy*WID + gx;
      av = A[g]; bv = Bv[g]; fv = F[g];
    }
    ta[ly][lx] = av; tb[ly][lx] = bv; tf[ly][lx] = fv;
  }
  __syncthreads();
  int blk = (blockIdx.z*gridDim.y + blockIdx.y)*gridDim.x + blockIdx.x;
  const float C1 = 1e-4f, C2 = 9e-4f;
  #pragma unroll
  for (int pass = 0; pass < 2; ++pass){
    for (int idx = tid; idx < 42*32; idx += 1024){
      int row = idx/32, col = idx%32;
      float sx=0.f, sf=0.f, sxx=0.f, sff=0.f, sxf=0.f;
      for (int j = 0; j < 11; ++j){
        float g = gw.g[j];
        float xv = pass ? tb[row][col+j] : ta[row][col+j];
        float fv = tf[row][col+j];
        sx += g*xv; sf += g*fv; sxx += g*xv*xv; sff += g*fv*fv; sxf += g*xv*fv;
      }
      hx[row][col]=sx; hf[row][col]=sf; hxx[row][col]=sxx; hff[row][col]=sff; hxf[row][col]=sxf;
    }
    __syncthreads();
    int ly = threadIdx.y, lx = threadIdx.x;
    float mu1=0.f, mu2=0.f, cxx=0.f, cff=0.f, cxf=0.f;
    for (int j = 0; j < 11; ++j){
      float g = gw.g[j];
      mu1 += g*hx[ly+j][lx]; mu2 += g*hf[ly+j][lx];
      cxx += g*hxx[ly+j][lx]; cff += g*hff[ly+j][lx]; cxf += g*hxf[ly+j][lx];
    }
    float m11 = mu1*mu1, m22 = mu2*mu2, m12 = mu1*mu2;
    float s1 = cxx - m11, s2 = cff - m22, s12 = cxf - m12;
    float m = ((2.f*m12 + C1)*(2.f*s12 + C2)) / ((m11 + m22 + C1)*(s1 + s2 + C2));
    red[tid] = m; __syncthreads();
    for (int o = 512; o > 0; o >>= 1){ if (tid < o) red[tid] += red[tid+o]; __syncthreads(); }
    if (tid == 0){ if (pass) psb[blk] = red[0]; else psa[blk] = red[0]; }
    __syncthreads();
  }
}

// ---------- box blur 9 + halo/bloom sums + fused L1 ----------
__global__ __launch_bounds__(1024) void hb_k(const float* __restrict__ A, const float* __restrict__ Bv,
                                             const float* __restrict__ F, const float* __restrict__ sal,
                                             const float* __restrict__ scal,
                                             const unsigned char* __restrict__ ml,
                                             const unsigned char* __restrict__ halo,
                                             const unsigned char* __restrict__ decay,
                                             float* __restrict__ p5){
  __shared__ float ti[40][40], tv[40][40], tf[40][40];
  __shared__ float hi_[40][32], hv_[40][32], hf_[40][32];
  __shared__ float red[1024];
  int b = blockIdx.z;
  int y0 = blockIdx.y*32, x0 = blockIdx.x*32;
  int tid = threadIdx.y*32 + threadIdx.x;
  size_t ib = (size_t)b*PIX;
  for (int idx = tid; idx < 40*40; idx += 1024){
    int ly = idx/40, lx = idx%40;
    int gy = y0 + ly - 4, gx = x0 + lx - 4;
    float a = 0.f, v = 0.f, f = 0.f;
    if (gy >= 0 && gy < HGT && gx >= 0 && gx < WID){
      size_t g = ib + (size_t)gy*WID + gx;
      a = A[g]; v = Bv[g]; f = F[g];
    }
    ti[ly][lx] = a; tv[ly][lx] = v; tf[ly][lx] = f;
  }
  __syncthreads();
  for (int idx = tid; idx < 40*32; idx += 1024){
    int row = idx/32, col = idx%32;
    float si=0.f, sv=0.f, sf=0.f;
    for (int j = 0; j < 9; ++j){ si += ti[row][col+j]; sv += tv[row][col+j]; sf += tf[row][col+j]; }
    hi_[row][col]=si; hv_[row][col]=sv; hf_[row][col]=sf;
  }
  __syncthreads();
  int ly = threadIdx.y, lx = threadIdx.x;
  float si=0.f, sv=0.f, sf=0.f;
  for (int j = 0; j < 9; ++j){ si += hi_[ly+j][lx]; sv += hv_[ly+j][lx]; sf += hf_[ly+j][lx]; }
  const float inv81 = 1.f/81.f;
  float ib_ = si*inv81, vb_ = sv*inv81;
  float fb_ = fminf(fmaxf(sf*inv81, 0.f), 1.f);
  int gy = y0 + ly, gx = x0 + lx;
  size_t g = ib + (size_t)gy*WID + gx;
  float q90s = scal[b*16 + S_Q90S], kM = scal[b*16 + S_KM];
  float salv = sal[g];
  float M = 1.f/(1.f + expf(-kM*(salv - q90s)));
  float mh = (halo[g] && !ml[g] && decay[g]) ? 1.f : 0.f;
  float v1 = mh*fmaxf(fb_ - ib_, 0.f);
  float v3 = M*fmaxf(fb_ - vb_, 0.f);
  // fused L1
  float a = ti[ly+4][lx+4], v = tv[ly+4][lx+4], f = tf[ly+4][lx+4];
  float imx = fmaxf(a, v), imn = fminf(a, v);
  bool irb = a > scal[b*16 + S_THR_IR];
  bool visb = v > scal[b*16 + S_THR_VIS];
  bool viss = v > scal[b*16 + S_THR_SUP];
  float salient = visb ? imn : imx;
  if (viss && irb) salient = imx;
  float target = M*salient + (1.f - M)*imx;
  float l1v = fabsf(f - target);

  float vals[5] = {v1, mh, v3, M, l1v};
  float sums[5];
  for (int q = 0; q < 5; ++q){
    red[tid] = vals[q]; __syncthreads();
    for (int o = 512; o > 0; o >>= 1){ if (tid < o) red[tid] += red[tid+o]; __syncthreads(); }
    sums[q] = red[0]; __syncthreads();
  }
  if (tid == 0){
    int blk = (blockIdx.z*gridDim.y + blockIdx.y)*gridDim.x + blockIdx.x;
    for (int q = 0; q < 5; ++q) p5[blk*5+q] = sums[q];
  }
}

// ---------- final reduction ----------
__device__ float blk_sum_1024(float v, float* red){
  int t = threadIdx.x;
  red[t] = v; __syncthreads();
  for (int o = 512; o > 0; o >>= 1){ if (t < o) red[t] += red[t+o]; __syncthreads(); }
  float s = red[0]; __syncthreads();
  return s;
}

__global__ __launch_bounds__(1024) void final_k(const float* __restrict__ pg,
                                                const float* __restrict__ psa, const float* __restrict__ psb,
                                                const float* __restrict__ p5, float* __restrict__ out){
  __shared__ float red[1024];
  int t = threadIdx.x;
  float v;
  v = pg[t];  float sumG = blk_sum_1024(v, red);
  v = psa[t]; float sA   = blk_sum_1024(v, red);
  v = psb[t]; float sB   = blk_sum_1024(v, red);
  float s5[5];
  for (int q = 0; q < 5; ++q){
    v = p5[t*5+q];
    s5[q] = blk_sum_1024(v, red);
  }
  if (t == 0){
    const float inv = 1.f/(float)NPIX;
    float loss_l1 = 15.f*s5[4]*inv;
    float loss_grad = 14.f*sumG*inv;
    float loss_ssim = 20.f*(1.f - 0.5f*sA*inv - 0.5f*sB*inv);
    float lh = s5[0] / fmaxf(s5[1] + 1e-6f, 1.f);
    float lb = s5[2] / fmaxf(s5[3] + 1e-6f, 1.f);
    float whb = 0.3f*lh + 0.6f*lb;
    out[0] = loss_l1 + loss_grad + loss_ssim + whb;
    out[1] = loss_grad;
    out[2] = loss_l1;
    out[3] = loss_ssim;
    out[4] = whb;
  }
}

// ---------- host ----------
extern "C" void kernel_launch(void* const* d_in, const int* in_sizes, int n_in,
                              void* d_out, int out_size, void* d_ws, size_t ws_size,
                              hipStream_t stream) {
  const float* A  = (const float*)d_in[0];
  const float* Bv = (const float*)d_in[1];
  const float* F  = (const float*)d_in[2];
  float* out = (float*)d_out;
  char* w = (char*)d_ws;

  float* sal = (float*)(w + OFF_SAL);
  float* ero = (float*)(w + OFF_ERO);
  unsigned char* ml    = (unsigned char*)(w + OFF_ML);
  unsigned char* halo  = (unsigned char*)(w + OFF_HALO);
  unsigned char* decay = (unsigned char*)(w + OFF_DECAY);
  int* cnt = (int*)(w + OFF_CNT);
  int* pts = (int*)(w + OFF_PTS);
  unsigned* h1 = (unsigned*)(w + OFF_H1);
  unsigned* h2 = (unsigned*)(w + OFF_H2);
  unsigned* h3 = (unsigned*)(w + OFF_H3);
  int2* st1 = (int2*)(w + OFF_ST1);
  int2* st2 = (int2*)(w + OFF_ST2);
  float* ost  = (float*)(w + OFF_OST);
  float* scal = (float*)(w + OFF_SCAL);
  float* spart= (float*)(w + OFF_SPART);
  float* pg  = (float*)(w + OFF_PG);
  float* psa = (float*)(w + OFF_PSA);
  float* psb = (float*)(w + OFF_PSB);
  float* p5  = (float*)(w + OFF_P5);

  dim3 b256(256), g4096(NPIX/256);
  dim3 gt(WID/32, HGT/32, BATCH), bt(32, 32);

  // ---- rank positions ----
  auto mkrank = [](double q, int* k0, double* fr){
    double pos = q*(double)(PIX-1);
    double fl = floor(pos);
    *k0 = (int)fl; *fr = pos - fl;
  };
  int kA70, kA97, kB40, kB85, kB97, kS90, kS97;
  double fA70, fA97, fB40, fB85, fB97, fS90, fS97;
  mkrank(0.70, &kA70, &fA70); mkrank(0.97, &kA97, &fA97);
  mkrank(0.40, &kB40, &fB40); mkrank(0.85, &kB85, &fB85); mkrank(0.97, &kB97, &fB97);
  mkrank(0.90, &kS90, &fS90); mkrank(0.97, &kS97, &fS97);

  // ---- zero hist + decay/cnt up front ----
  hipMemsetAsync(w + OFF_H1, 0, QHIST_BYTES, stream);
  hipMemsetAsync(w + OFF_DECAY, 0, (size_t)NPIX + 64, stream);

  // ---- saliency: fused tiled opening per k, sal = max_k(A - opening), raw (no normalize) ----
  erode_k<4><<<gt, bt, 0, stream>>>(A, ero);
  dilate_k<4,1,0><<<gt, bt, 0, stream>>>(ero, A, sal, spart);
  erode_k<7><<<gt, bt, 0, stream>>>(A, ero);
  dilate_k<7,0,0><<<gt, bt, 0, stream>>>(ero, A, sal, spart);
  erode_k<15><<<gt, bt, 0, stream>>>(A, ero);
  dilate_k<15,0,1><<<gt, bt, 0, stream>>>(ero, A, sal, spart);
  salfin_k<<<BATCH, 256, 0, stream>>>(spart, scal);

  // ---- one quantile pipeline: A(4 ranks) + B(6) + raw sal(4) ----
  QRanks ra{};
  {
    int rr[14] = {kA70, kA70+1, kA97, kA97+1,
                  kB40, kB40+1, kB85, kB85+1, kB97, kB97+1,
                  kS90, kS90+1, kS97, kS97+1};
    int aa[14] = {0,0,0,0, 1,1,1,1,1,1, 2,2,2,2};
    for (int i = 0; i < 14; ++i){ ra.rank[i]=rr[i]; ra.arr[i]=aa[i]; }
    ra.nr = 14;
  }
  qh1_k<<<dim3(QH_BLOCKS, BATCH, 3), b256, 0, stream>>>(A, Bv, sal, h1);
  qs1_k<<<3*BATCH, 1024, 0, stream>>>(h1, ra, st1);
  qh2_k<<<dim3(QH_BLOCKS, BATCH, 14), b256, 0, stream>>>(A, Bv, sal, st1, ra, h2);
  qs2_k<<<14*BATCH, 1024, 0, stream>>>(h2, st1, ra, st2);
  qh3_k<<<dim3(QH_BLOCKS, BATCH, 14), b256, 0, stream>>>(A, Bv, sal, st1, st2, ra, h3);
  qs3_k<<<14*BATCH, 256, 0, stream>>>(h3, st1, st2, ost);
  FracArg fr{(float)fA70, (float)fA97, (float)fB40, (float)fB85, (float)fB97, (float)fS90, (float)fS97};
  finq_k<<<1, 16, 0, stream>>>(ost, scal, fr);

  // ---- masks ----
  mlight_compact_k<<<g4096, b256, 0, stream>>>(A, Bv, sal, scal, ml, cnt, pts);
  paint_k<<<dim3(256, BATCH), 128, 0, stream>>>(cnt, pts, decay);
  brighthalo_k<<<gt, bt, 0, stream>>>(A, scal, halo);

  // ---- losses ----
  grad_k<<<gt, bt, 0, stream>>>(A, Bv, F, pg);
  GaussArg ga{};
  {
    double g[11], s = 0.0;
    for (int i = 0; i < 11; ++i){ double d = (double)(i-5); g[i] = exp(-(d*d)/4.5); s += g[i]; }
    for (int i = 0; i < 11; ++i) ga.g[i] = (float)(g[i]/s);
  }
  ssim2_k<<<gt, bt, 0, stream>>>(A, Bv, F, psa, psb, ga);
  hb_k<<<gt, bt, 0, stream>>>(A, Bv, F, sal, scal, ml, halo, decay, p5);

  final_k<<<1, 1024, 0, stream>>>(pg, psa, psb, p5, out);
}